// Round 1
// baseline (282.809 us; speedup 1.0000x reference)
//
#include <hip/hip_runtime.h>
#include <hip/hip_bf16.h>
#include <stdint.h>

typedef __bf16 bf16x8 __attribute__((ext_vector_type(8)));
typedef float f32x4 __attribute__((ext_vector_type(4)));
typedef unsigned short u16;
typedef u16 ushort4v __attribute__((ext_vector_type(4)));
typedef u16 ushort8v __attribute__((ext_vector_type(8)));

__device__ __forceinline__ u16 f2bf(float f) {
    union { float f; uint32_t u; } v; v.f = f;
    uint32_t u = v.u + 0x7FFFu + ((v.u >> 16) & 1u);
    return (u16)(u >> 16);
}
__device__ __forceinline__ float bf2f(u16 b) {
    union { uint32_t u; float f; } v; v.u = ((uint32_t)b) << 16;
    return v.f;
}
__device__ __forceinline__ float silu_f(float v) {
    return v / (1.0f + __expf(-v));
}
__device__ __forceinline__ void gload_lds16(const u16* g, u16* l) {
    __builtin_amdgcn_global_load_lds(
        (const __attribute__((address_space(1))) void*)g,
        (__attribute__((address_space(3))) void*)l, 16, 0, 0);
}

// ---------------- prep kernels ----------------
__global__ void cvt_bf16_k(const float* __restrict__ src, u16* __restrict__ dst, int n4) {
    int i = blockIdx.x * 256 + threadIdx.x;
    if (i < n4) {
        float4 v = *(const float4*)&src[(int64_t)i * 4];
        ushort4v o = { f2bf(v.x), f2bf(v.y), f2bf(v.z), f2bf(v.w) };
        *(ushort4v*)&dst[(int64_t)i * 4] = o;
    }
}

// dst[c][r] = bf16(src[r][c]); R,C multiples of 32
__global__ __launch_bounds__(256) void trans_cvt_k(
        const float* __restrict__ src, u16* __restrict__ dst, int R, int C) {
    __shared__ float t[32][33];
    const int bc = blockIdx.x, br = blockIdx.y;
    const int tx = threadIdx.x & 31, ty = threadIdx.x >> 5;
#pragma unroll
    for (int i = 0; i < 4; i++) {
        int r = ty + i * 8;
        t[r][tx] = src[(int64_t)(br * 32 + r) * C + bc * 32 + tx];
    }
    __syncthreads();
#pragma unroll
    for (int i = 0; i < 4; i++) {
        int c = ty + i * 8;
        dst[(int64_t)(bc * 32 + c) * R + br * 32 + tx] = f2bf(t[tx][c]);
    }
}

// W_xproj (2048x33) -> Wxt (48x2048) bf16, rows 33..47 zero
__global__ void prep_wxt_k(const float* __restrict__ wx, u16* __restrict__ wxt) {
    int idx = blockIdx.x * 256 + threadIdx.x;
    if (idx < 48 * 2048) {
        int j = idx >> 11, d = idx & 2047;
        wxt[idx] = (j < 33) ? f2bf(wx[d * 33 + j]) : (u16)0;
    }
}

// ---------------- 128x128 bf16 MFMA GEMM, C = A * Bt^T ----------------
template<bool OUT_BF16>
__global__ __launch_bounds__(256) void gemm_bt(
        const u16* __restrict__ A, const u16* __restrict__ Bt,
        void* __restrict__ Cout, int M, int N, int K, int lda, int ldc) {
    __shared__ __align__(16) u16 As[128 * 32];
    __shared__ __align__(16) u16 Bs[128 * 32];
    const int tid = threadIdx.x;
    const int wave = tid >> 6;
    const int lane = tid & 63;
    const int bm = blockIdx.x, bn = blockIdx.y;
    const int wr = wave >> 1, wc = wave & 1;
    const int fr = lane & 15, fq = lane >> 4;

    const u16* ag0 = A + (int64_t)(bm * 128 + (tid >> 2)) * lda + (tid & 3) * 8;
    const u16* ag1 = ag0 + (int64_t)64 * lda;
    const u16* bg0 = Bt + (int64_t)(bn * 128 + (tid >> 2)) * K + (tid & 3) * 8;
    const u16* bg1 = bg0 + (int64_t)64 * K;
    u16* asd0 = &As[wave * 512]; u16* asd1 = &As[2048 + wave * 512];
    u16* bsd0 = &Bs[wave * 512]; u16* bsd1 = &Bs[2048 + wave * 512];

    const int a_base = (wr * 64 + fr) * 32 + fq * 8;
    const int b_base = (wc * 64 + fr) * 32 + fq * 8;

    f32x4 acc[4][4] = {};

    for (int k0 = 0; k0 < K; k0 += 32) {
        gload_lds16(ag0 + k0, asd0);
        gload_lds16(ag1 + k0, asd1);
        gload_lds16(bg0 + k0, bsd0);
        gload_lds16(bg1 + k0, bsd1);
        __syncthreads();
        bf16x8 af[4], bfv[4];
#pragma unroll
        for (int m = 0; m < 4; m++) af[m] = *(const bf16x8*)&As[a_base + m * 512];
#pragma unroll
        for (int n = 0; n < 4; n++) bfv[n] = *(const bf16x8*)&Bs[b_base + n * 512];
#pragma unroll
        for (int m = 0; m < 4; m++)
#pragma unroll
            for (int n = 0; n < 4; n++)
                acc[m][n] = __builtin_amdgcn_mfma_f32_16x16x32_bf16(af[m], bfv[n], acc[m][n], 0, 0, 0);
        __syncthreads();
    }

#pragma unroll
    for (int m = 0; m < 4; m++) {
#pragma unroll
        for (int n = 0; n < 4; n++) {
            const int col = bn * 128 + wc * 64 + n * 16 + fr;
#pragma unroll
            for (int r = 0; r < 4; r++) {
                const int row = bm * 128 + wr * 64 + m * 16 + fq * 4 + r;
                if constexpr (OUT_BF16)
                    ((u16*)Cout)[(int64_t)row * ldc + col] = f2bf(acc[m][n][r]);
                else
                    ((float*)Cout)[(int64_t)row * ldc + col] = acc[m][n][r];
            }
        }
    }
}

// ---------------- depthwise conv(4) + bias + SiLU ----------------
__global__ __launch_bounds__(256) void conv_silu_k(
        const u16* __restrict__ xz, const float* __restrict__ cw,
        const float* __restrict__ cb, u16* __restrict__ xc) {
    const int blk = blockIdx.x;
    const int b = blk >> 9;
    const int l0 = (blk & 511) << 2;
    const int d0 = threadIdx.x * 8;
    float w[8][4], bias[8];
#pragma unroll
    for (int j = 0; j < 8; j++) {
        float4 wv = *(const float4*)&cw[(d0 + j) * 4];
        w[j][0] = wv.x; w[j][1] = wv.y; w[j][2] = wv.z; w[j][3] = wv.w;
        bias[j] = cb[d0 + j];
    }
    float xp[7][8];
#pragma unroll
    for (int r = 0; r < 7; r++) {
        int l = l0 - 3 + r;
        if (l < 0) {
#pragma unroll
            for (int j = 0; j < 8; j++) xp[r][j] = 0.f;
        } else {
            ushort8v v = *(const ushort8v*)&xz[((int64_t)(b * 2048 + l)) * 4096 + d0];
#pragma unroll
            for (int j = 0; j < 8; j++) xp[r][j] = bf2f(v[j]);
        }
    }
#pragma unroll
    for (int li = 0; li < 4; li++) {
        ushort8v o;
#pragma unroll
        for (int j = 0; j < 8; j++) {
            float s = bias[j];
#pragma unroll
            for (int k = 0; k < 4; k++) s += w[j][k] * xp[li + k][j];
            o[j] = f2bf(silu_f(s));
        }
        *(ushort8v*)&xc[((int64_t)(b * 2048 + l0 + li)) * 2048 + d0] = o;
    }
}

// ---------------- ssm projection (K split by 4), spart: [4][8192][48] ----------------
__global__ __launch_bounds__(256) void ssm_proj_k(
        const u16* __restrict__ xc, const u16* __restrict__ wxt,
        float* __restrict__ spart) {
    const int gw = (blockIdx.x << 2) + (threadIdx.x >> 6);
    const int lane = threadIdx.x & 63;
    const int rb = gw >> 2, kc = gw & 3;
    const int fr = lane & 15, fq = lane >> 4;
    const u16* ap = xc + (int64_t)(rb * 16 + fr) * 2048 + kc * 512 + fq * 8;
    const u16* bp = wxt + (int64_t)fr * 2048 + kc * 512 + fq * 8;
    f32x4 acc0 = {}, acc1 = {}, acc2 = {};
#pragma unroll 4
    for (int k = 0; k < 512; k += 32) {
        bf16x8 av = *(const bf16x8*)(ap + k);
        bf16x8 b0 = *(const bf16x8*)(bp + k);
        bf16x8 b1 = *(const bf16x8*)(bp + 16 * 2048 + k);
        bf16x8 b2 = *(const bf16x8*)(bp + 32 * 2048 + k);
        acc0 = __builtin_amdgcn_mfma_f32_16x16x32_bf16(av, b0, acc0, 0, 0, 0);
        acc1 = __builtin_amdgcn_mfma_f32_16x16x32_bf16(av, b1, acc1, 0, 0, 0);
        acc2 = __builtin_amdgcn_mfma_f32_16x16x32_bf16(av, b2, acc2, 0, 0, 0);
    }
    float* sp = spart + ((int64_t)kc * 8192 + rb * 16) * 48;
#pragma unroll
    for (int r = 0; r < 4; r++) {
        int ro = (fq * 4 + r) * 48;
        sp[ro + fr] = acc0[r];
        sp[ro + 16 + fr] = acc1[r];
        sp[ro + 32 + fr] = acc2[r];
    }
}

__global__ __launch_bounds__(256) void ssm_fin_k(
        const float* __restrict__ spart, float* __restrict__ dB,
        float* __restrict__ Cm) {
    const int row = blockIdx.x * 256 + threadIdx.x;
    const float* sp = spart + (int64_t)row * 48;
    float s[33];
#pragma unroll
    for (int j = 0; j < 33; j++)
        s[j] = sp[j] + sp[8192 * 48 + j] + sp[2 * 8192 * 48 + j] + sp[3 * 8192 * 48 + j];
    float d0v = s[0];
    float delta = (d0v > 20.f) ? d0v : log1pf(__expf(d0v));
#pragma unroll
    for (int n = 0; n < 16; n++) {
        dB[(int64_t)row * 16 + n] = delta * s[1 + n] * (1.0f / 2048.0f);
        Cm[(int64_t)row * 16 + n] = s[17 + n];
    }
}

__global__ __launch_bounds__(256) void h_part_k(
        const u16* __restrict__ xc, const float* __restrict__ dB,
        float* __restrict__ hp) {
    const int blk = blockIdx.x;
    const int dt = blk & 7, b = (blk >> 3) & 3, lc = blk >> 5;
    const int d = dt * 256 + threadIdx.x;
    const u16* xp = xc + ((int64_t)(b * 2048 + lc * 256)) * 2048 + d;
    const float* dbp = dB + (int64_t)(b * 2048 + lc * 256) * 16;
    float acc[16] = {};
    for (int l = 0; l < 256; l++) {
        float xv = bf2f(xp[(int64_t)l * 2048]);
#pragma unroll
        for (int n = 0; n < 16; n++) acc[n] += xv * dbp[l * 16 + n];
    }
    float* o = hp + ((int64_t)((lc * 4 + b) * 2048 + d)) * 16;
#pragma unroll
    for (int n = 0; n < 16; n++) o[n] = acc[n];
}

__global__ void h_red_k(const float* __restrict__ hp, float* __restrict__ h) {
    const int i = blockIdx.x * 256 + threadIdx.x;  // < 131072
    float s = 0.f;
#pragma unroll
    for (int c = 0; c < 8; c++) s += hp[(int64_t)c * 131072 + i];
    h[i] = s;
}

__global__ __launch_bounds__(256) void y_gate_k(
        u16* __restrict__ xz, const u16* __restrict__ xc,
        const float* __restrict__ h, const float* __restrict__ Cm,
        const float* __restrict__ Dp) {
    const int blk = blockIdx.x;
    const int lc = blk & 63, dt = (blk >> 6) & 1, b = blk >> 7;
    const int d0 = dt * 1024 + threadIdx.x * 4;
    const float* hpp = h + ((int64_t)(b * 2048 + d0)) * 16;
    float hreg[4][16];
#pragma unroll
    for (int i = 0; i < 4; i++)
#pragma unroll
        for (int n = 0; n < 16; n++) hreg[i][n] = hpp[i * 16 + n];
    float Dv[4];
#pragma unroll
    for (int i = 0; i < 4; i++) Dv[i] = Dp[d0 + i];
    __shared__ float Cs[32][16];
    if (threadIdx.x < 128)
        ((float4*)&Cs[0][0])[threadIdx.x] =
            ((const float4*)(Cm + (int64_t)(b * 2048 + lc * 32) * 16))[threadIdx.x];
    __syncthreads();
    for (int li = 0; li < 32; li++) {
        const int64_t rowz = (int64_t)(b * 2048 + lc * 32 + li);
        ushort4v xcv = *(const ushort4v*)&xc[rowz * 2048 + d0];
        ushort4v zv = *(const ushort4v*)&xz[rowz * 4096 + 2048 + d0];
        ushort4v o;
#pragma unroll
        for (int i = 0; i < 4; i++) {
            float s = Dv[i] * bf2f(xcv[i]);
#pragma unroll
            for (int n = 0; n < 16; n++) s += hreg[i][n] * Cs[li][n];
            o[i] = f2bf(s * silu_f(bf2f(zv[i])));
        }
        *(ushort4v*)&xz[rowz * 4096 + d0] = o;
    }
}

extern "C" void kernel_launch(void* const* d_in, const int* in_sizes, int n_in,
                              void* d_out, int out_size, void* d_ws, size_t ws_size,
                              hipStream_t stream) {
    (void)in_sizes; (void)n_in; (void)out_size; (void)ws_size;
    const float* x      = (const float*)d_in[0];
    const float* W_in   = (const float*)d_in[1];
    const float* conv_w = (const float*)d_in[2];
    const float* conv_b = (const float*)d_in[3];
    const float* W_xp   = (const float*)d_in[4];
    const float* Dp     = (const float*)d_in[6];   // d_in[5] = A_log, unused by reference
    const float* W_out  = (const float*)d_in[7];
    float* out = (float*)d_out;
    char* ws = (char*)d_ws;

    u16*   x_bf   = (u16*)(ws);                   // 16,777,216 B (dead after GEMM1)
    float* spart  = (float*)(ws);                 // alias: 6,291,456
    float* dB     = (float*)(ws + 6291456);       // 524,288
    float* Cm     = (float*)(ws + 6815744);       // 524,288
    float* hp     = (float*)(ws + 7340032);       // 4,194,304
    float* h      = (float*)(ws + 11534336);      // 524,288
    u16*   Wt_in  = (u16*)(ws + 16777216);        // 8,388,608
    u16*   Wt_out = (u16*)(ws + 25165824);        // 4,194,304
    u16*   Wxt    = (u16*)(ws + 29360128);        // 196,608
    u16*   xz     = (u16*)(ws + 29556736);        // 67,108,864
    u16*   xcv    = (u16*)(ws + 96665600);        // 33,554,432  (total ~130 MB)

    cvt_bf16_k<<<8192, 256, 0, stream>>>(x, x_bf, 2097152);
    trans_cvt_k<<<dim3(128, 32), 256, 0, stream>>>(W_in, Wt_in, 1024, 4096);
    trans_cvt_k<<<dim3(32, 64), 256, 0, stream>>>(W_out, Wt_out, 2048, 1024);
    prep_wxt_k<<<384, 256, 0, stream>>>(W_xp, Wxt);
    gemm_bt<true><<<dim3(64, 32), 256, 0, stream>>>(x_bf, Wt_in, xz, 8192, 4096, 1024, 1024, 4096);
    conv_silu_k<<<2048, 256, 0, stream>>>(xz, conv_w, conv_b, xcv);
    ssm_proj_k<<<512, 256, 0, stream>>>(xcv, Wxt, spart);
    ssm_fin_k<<<32, 256, 0, stream>>>(spart, dB, Cm);
    h_part_k<<<256, 256, 0, stream>>>(xcv, dB, hp);
    h_red_k<<<512, 256, 0, stream>>>(hp, h);
    y_gate_k<<<512, 256, 0, stream>>>(xz, xcv, h, Cm, Dp);
    gemm_bt<false><<<dim3(64, 8), 256, 0, stream>>>(xz, Wt_out, out, 8192, 1024, 2048, 4096, 1024);
}

// Round 2
// 282.515 us; speedup vs baseline: 1.0010x; 1.0010x over previous
//
#include <hip/hip_runtime.h>
#include <hip/hip_bf16.h>
#include <stdint.h>

typedef __bf16 bf16x8 __attribute__((ext_vector_type(8)));
typedef float f32x4 __attribute__((ext_vector_type(4)));
typedef unsigned short u16;
typedef u16 ushort4v __attribute__((ext_vector_type(4)));
typedef u16 ushort8v __attribute__((ext_vector_type(8)));

__device__ __forceinline__ u16 f2bf(float f) {
    union { float f; uint32_t u; } v; v.f = f;
    uint32_t u = v.u + 0x7FFFu + ((v.u >> 16) & 1u);
    return (u16)(u >> 16);
}
__device__ __forceinline__ float bf2f(u16 b) {
    union { uint32_t u; float f; } v; v.u = ((uint32_t)b) << 16;
    return v.f;
}
__device__ __forceinline__ float silu_f(float v) {
    return v / (1.0f + __expf(-v));
}
__device__ __forceinline__ void gload_lds16(const u16* g, u16* l) {
    __builtin_amdgcn_global_load_lds(
        (const __attribute__((address_space(1))) void*)g,
        (__attribute__((address_space(3))) void*)l, 16, 0, 0);
}

// ---------------- prep kernels ----------------
__global__ void cvt_bf16_k(const float* __restrict__ src, u16* __restrict__ dst, int n4) {
    int i = blockIdx.x * 256 + threadIdx.x;
    if (i < n4) {
        float4 v = *(const float4*)&src[(int64_t)i * 4];
        ushort4v o = { f2bf(v.x), f2bf(v.y), f2bf(v.z), f2bf(v.w) };
        *(ushort4v*)&dst[(int64_t)i * 4] = o;
    }
}

// dst[c][r] = bf16(src[r][c]); R,C multiples of 32
__global__ __launch_bounds__(256) void trans_cvt_k(
        const float* __restrict__ src, u16* __restrict__ dst, int R, int C) {
    __shared__ float t[32][33];
    const int bc = blockIdx.x, br = blockIdx.y;
    const int tx = threadIdx.x & 31, ty = threadIdx.x >> 5;
#pragma unroll
    for (int i = 0; i < 4; i++) {
        int r = ty + i * 8;
        t[r][tx] = src[(int64_t)(br * 32 + r) * C + bc * 32 + tx];
    }
    __syncthreads();
#pragma unroll
    for (int i = 0; i < 4; i++) {
        int c = ty + i * 8;
        dst[(int64_t)(bc * 32 + c) * R + br * 32 + tx] = f2bf(t[tx][c]);
    }
}

// W_xproj (2048x33) -> Wxt (48x2048) bf16, rows 33..47 zero
__global__ void prep_wxt_k(const float* __restrict__ wx, u16* __restrict__ wxt) {
    int idx = blockIdx.x * 256 + threadIdx.x;
    if (idx < 48 * 2048) {
        int j = idx >> 11, d = idx & 2047;
        wxt[idx] = (j < 33) ? f2bf(wx[d * 33 + j]) : (u16)0;
    }
}

// ---------------- 256x128 bf16 MFMA GEMM, C = A * Bt^T ----------------
// Deep-pipelined: BK=64, 3-buffer LDS ring, stage kt+2 while computing kt,
// counted vmcnt(6) (never 0 mid-loop), XOR-swizzled LDS (T2, both-sides),
// XCD-swizzled grid (T1), setprio around MFMA clusters (T5).
// A: M x K row-major (row stride lda), Bt: N x K row-major (row stride ldb=K),
// C: M x N (row stride ldc). grid = (M/256)*nbn blocks (1D), 512 threads.
template<bool OUT_BF16>
__global__ __launch_bounds__(512) void gemm_bt2(
        const u16* __restrict__ A, const u16* __restrict__ Bt,
        void* __restrict__ Cout, int nbn, int NT, int lda, int ldc, int ldb) {
    // A bufs: 3 x 256x64 u16 (32KB each); B bufs: 3 x 128x64 u16 (16KB each)
    __shared__ __align__(16) u16 As[3 * 16384];
    __shared__ __align__(16) u16 Bs[3 * 8192];
    const int tid = threadIdx.x;
    const int wave = tid >> 6;
    const int lane = tid & 63;

    // T1: bijective XCD swizzle (gridDim.x % 8 == 0 for both call sites)
    const int nwg = gridDim.x;
    const int cpx = nwg >> 3;
    const int swz = (blockIdx.x & 7) * cpx + (blockIdx.x >> 3);
    const int bm = swz / nbn, bn = swz % nbn;

    const int wr = wave >> 1, wc = wave & 1;       // 4M x 2N waves
    const int fr = lane & 15, fq = lane >> 4;

    // stage-side addressing: per-lane global source pre-swizzled (rule #21)
    const int rj = tid >> 3;                        // row-within-issue 0..63
    const int sslot = (tid & 7) ^ (rj & 7);         // source 16B slot
    const u16* agp[4];
#pragma unroll
    for (int j = 0; j < 4; ++j)
        agp[j] = A + (int64_t)(bm * 256 + j * 64 + rj) * lda + sslot * 8;
    const u16* bgp[2];
#pragma unroll
    for (int j = 0; j < 2; ++j)
        bgp[j] = Bt + (int64_t)(bn * 128 + j * 64 + rj) * ldb + sslot * 8;

    // read-side fragment offsets (u16 units), swizzled: slot = (kk*4+fq)^(fr&7)
    int aoff[4], boff[4];
#pragma unroll
    for (int m = 0; m < 4; ++m)
        aoff[m] = (wr * 64 + m * 16 + fr) * 64 + ((fq ^ (fr & 7)) * 8);
#pragma unroll
    for (int n = 0; n < 4; ++n)
        boff[n] = (wc * 64 + n * 16 + fr) * 64 + ((fq ^ (fr & 7)) * 8);
    // kk=1 fragment: slot ^= 4  ->  u16 index ^= 32 (row*64 has no bit 5)

    f32x4 acc[4][4] = {};

    // prologue: stage tiles 0 (buf0) and 1 (buf1); wait tile0 (6 loads of
    // tile1 stay in flight), then barrier so all waves' slices are visible.
#pragma unroll
    for (int j = 0; j < 4; ++j) gload_lds16(agp[j],      &As[j * 4096 + wave * 512]);
#pragma unroll
    for (int j = 0; j < 2; ++j) gload_lds16(bgp[j],      &Bs[j * 4096 + wave * 512]);
#pragma unroll
    for (int j = 0; j < 4; ++j) gload_lds16(agp[j] + 64, &As[16384 + j * 4096 + wave * 512]);
#pragma unroll
    for (int j = 0; j < 2; ++j) gload_lds16(bgp[j] + 64, &Bs[8192 + j * 4096 + wave * 512]);
    asm volatile("s_waitcnt vmcnt(6)" ::: "memory");
    __builtin_amdgcn_s_barrier();

    int pc = 0;  // compute-buffer index (= kt % 3)
    for (int kt = 0; kt < NT; ++kt) {
        int ps = pc + 2; if (ps >= 3) ps -= 3;
        if (kt + 2 < NT) {
            // stage tile kt+2 into buf ps (last read at iter kt-1; drained by
            // that iter's MFMA lgkmcnt waits + end-of-iter barrier -> safe)
            const int kc = (kt + 2) * 64;
#pragma unroll
            for (int j = 0; j < 4; ++j)
                gload_lds16(agp[j] + kc, &As[ps * 16384 + j * 4096 + wave * 512]);
#pragma unroll
            for (int j = 0; j < 2; ++j)
                gload_lds16(bgp[j] + kc, &Bs[ps * 8192 + j * 4096 + wave * 512]);
        }
        const u16* Ab = &As[pc * 16384];
        const u16* Bb = &Bs[pc * 8192];
        bf16x8 a0[4], b0[4], a1[4], b1[4];
#pragma unroll
        for (int m = 0; m < 4; ++m) a0[m] = *(const bf16x8*)(Ab + aoff[m]);
#pragma unroll
        for (int n = 0; n < 4; ++n) b0[n] = *(const bf16x8*)(Bb + boff[n]);
        __builtin_amdgcn_s_setprio(1);
#pragma unroll
        for (int m = 0; m < 4; ++m)
#pragma unroll
            for (int n = 0; n < 4; ++n)
                acc[m][n] = __builtin_amdgcn_mfma_f32_16x16x32_bf16(a0[m], b0[n], acc[m][n], 0, 0, 0);
        __builtin_amdgcn_s_setprio(0);
#pragma unroll
        for (int m = 0; m < 4; ++m) a1[m] = *(const bf16x8*)(Ab + (aoff[m] ^ 32));
#pragma unroll
        for (int n = 0; n < 4; ++n) b1[n] = *(const bf16x8*)(Bb + (boff[n] ^ 32));
        __builtin_amdgcn_s_setprio(1);
#pragma unroll
        for (int m = 0; m < 4; ++m)
#pragma unroll
            for (int n = 0; n < 4; ++n)
                acc[m][n] = __builtin_amdgcn_mfma_f32_16x16x32_bf16(a1[m], b1[n], acc[m][n], 0, 0, 0);
        __builtin_amdgcn_s_setprio(0);
        // pin reads+MFMAs above the wait; then wait tile kt+1 landed (6 loads
        // of tile kt+2 remain in flight) and sync all waves.
        __builtin_amdgcn_sched_barrier(0);
        if (kt + 2 < NT) { asm volatile("s_waitcnt vmcnt(6)" ::: "memory"); }
        else             { asm volatile("s_waitcnt vmcnt(0)" ::: "memory"); }
        __builtin_amdgcn_s_barrier();
        if (++pc == 3) pc = 0;
    }

#pragma unroll
    for (int m = 0; m < 4; ++m) {
#pragma unroll
        for (int n = 0; n < 4; ++n) {
            const int col = bn * 128 + wc * 64 + n * 16 + fr;
#pragma unroll
            for (int r = 0; r < 4; ++r) {
                const int row = bm * 256 + wr * 64 + m * 16 + fq * 4 + r;
                if constexpr (OUT_BF16)
                    ((u16*)Cout)[(int64_t)row * ldc + col] = f2bf(acc[m][n][r]);
                else
                    ((float*)Cout)[(int64_t)row * ldc + col] = acc[m][n][r];
            }
        }
    }
}

// ---------------- depthwise conv(4) + bias + SiLU ----------------
__global__ __launch_bounds__(256) void conv_silu_k(
        const u16* __restrict__ xz, const float* __restrict__ cw,
        const float* __restrict__ cb, u16* __restrict__ xc) {
    const int blk = blockIdx.x;
    const int b = blk >> 9;
    const int l0 = (blk & 511) << 2;
    const int d0 = threadIdx.x * 8;
    float w[8][4], bias[8];
#pragma unroll
    for (int j = 0; j < 8; j++) {
        float4 wv = *(const float4*)&cw[(d0 + j) * 4];
        w[j][0] = wv.x; w[j][1] = wv.y; w[j][2] = wv.z; w[j][3] = wv.w;
        bias[j] = cb[d0 + j];
    }
    float xp[7][8];
#pragma unroll
    for (int r = 0; r < 7; r++) {
        int l = l0 - 3 + r;
        if (l < 0) {
#pragma unroll
            for (int j = 0; j < 8; j++) xp[r][j] = 0.f;
        } else {
            ushort8v v = *(const ushort8v*)&xz[((int64_t)(b * 2048 + l)) * 4096 + d0];
#pragma unroll
            for (int j = 0; j < 8; j++) xp[r][j] = bf2f(v[j]);
        }
    }
#pragma unroll
    for (int li = 0; li < 4; li++) {
        ushort8v o;
#pragma unroll
        for (int j = 0; j < 8; j++) {
            float s = bias[j];
#pragma unroll
            for (int k = 0; k < 4; k++) s += w[j][k] * xp[li + k][j];
            o[j] = f2bf(silu_f(s));
        }
        *(ushort8v*)&xc[((int64_t)(b * 2048 + l0 + li)) * 2048 + d0] = o;
    }
}

// ---------------- ssm projection (K split by 4), spart: [4][8192][48] ----------------
__global__ __launch_bounds__(256) void ssm_proj_k(
        const u16* __restrict__ xc, const u16* __restrict__ wxt,
        float* __restrict__ spart) {
    const int gw = (blockIdx.x << 2) + (threadIdx.x >> 6);
    const int lane = threadIdx.x & 63;
    const int rb = gw >> 2, kc = gw & 3;
    const int fr = lane & 15, fq = lane >> 4;
    const u16* ap = xc + (int64_t)(rb * 16 + fr) * 2048 + kc * 512 + fq * 8;
    const u16* bp = wxt + (int64_t)fr * 2048 + kc * 512 + fq * 8;
    f32x4 acc0 = {}, acc1 = {}, acc2 = {};
#pragma unroll 4
    for (int k = 0; k < 512; k += 32) {
        bf16x8 av = *(const bf16x8*)(ap + k);
        bf16x8 b0 = *(const bf16x8*)(bp + k);
        bf16x8 b1 = *(const bf16x8*)(bp + 16 * 2048 + k);
        bf16x8 b2 = *(const bf16x8*)(bp + 32 * 2048 + k);
        acc0 = __builtin_amdgcn_mfma_f32_16x16x32_bf16(av, b0, acc0, 0, 0, 0);
        acc1 = __builtin_amdgcn_mfma_f32_16x16x32_bf16(av, b1, acc1, 0, 0, 0);
        acc2 = __builtin_amdgcn_mfma_f32_16x16x32_bf16(av, b2, acc2, 0, 0, 0);
    }
    float* sp = spart + ((int64_t)kc * 8192 + rb * 16) * 48;
#pragma unroll
    for (int r = 0; r < 4; r++) {
        int ro = (fq * 4 + r) * 48;
        sp[ro + fr] = acc0[r];
        sp[ro + 16 + fr] = acc1[r];
        sp[ro + 32 + fr] = acc2[r];
    }
}

__global__ __launch_bounds__(256) void ssm_fin_k(
        const float* __restrict__ spart, float* __restrict__ dB,
        float* __restrict__ Cm) {
    const int row = blockIdx.x * 256 + threadIdx.x;
    const float* sp = spart + (int64_t)row * 48;
    float s[33];
#pragma unroll
    for (int j = 0; j < 33; j++)
        s[j] = sp[j] + sp[8192 * 48 + j] + sp[2 * 8192 * 48 + j] + sp[3 * 8192 * 48 + j];
    float d0v = s[0];
    float delta = (d0v > 20.f) ? d0v : log1pf(__expf(d0v));
#pragma unroll
    for (int n = 0; n < 16; n++) {
        dB[(int64_t)row * 16 + n] = delta * s[1 + n] * (1.0f / 2048.0f);
        Cm[(int64_t)row * 16 + n] = s[17 + n];
    }
}

__global__ __launch_bounds__(256) void h_part_k(
        const u16* __restrict__ xc, const float* __restrict__ dB,
        float* __restrict__ hp) {
    const int blk = blockIdx.x;
    const int dt = blk & 7, b = (blk >> 3) & 3, lc = blk >> 5;
    const int d = dt * 256 + threadIdx.x;
    const u16* xp = xc + ((int64_t)(b * 2048 + lc * 256)) * 2048 + d;
    const float* dbp = dB + (int64_t)(b * 2048 + lc * 256) * 16;
    float acc[16] = {};
    for (int l = 0; l < 256; l++) {
        float xv = bf2f(xp[(int64_t)l * 2048]);
#pragma unroll
        for (int n = 0; n < 16; n++) acc[n] += xv * dbp[l * 16 + n];
    }
    float* o = hp + ((int64_t)((lc * 4 + b) * 2048 + d)) * 16;
#pragma unroll
    for (int n = 0; n < 16; n++) o[n] = acc[n];
}

__global__ void h_red_k(const float* __restrict__ hp, float* __restrict__ h) {
    const int i = blockIdx.x * 256 + threadIdx.x;  // < 131072
    float s = 0.f;
#pragma unroll
    for (int c = 0; c < 8; c++) s += hp[(int64_t)c * 131072 + i];
    h[i] = s;
}

__global__ __launch_bounds__(256) void y_gate_k(
        u16* __restrict__ xz, const u16* __restrict__ xc,
        const float* __restrict__ h, const float* __restrict__ Cm,
        const float* __restrict__ Dp) {
    const int blk = blockIdx.x;
    const int lc = blk & 63, dt = (blk >> 6) & 1, b = blk >> 7;
    const int d0 = dt * 1024 + threadIdx.x * 4;
    const float* hpp = h + ((int64_t)(b * 2048 + d0)) * 16;
    float hreg[4][16];
#pragma unroll
    for (int i = 0; i < 4; i++)
#pragma unroll
        for (int n = 0; n < 16; n++) hreg[i][n] = hpp[i * 16 + n];
    float Dv[4];
#pragma unroll
    for (int i = 0; i < 4; i++) Dv[i] = Dp[d0 + i];
    __shared__ float Cs[32][16];
    if (threadIdx.x < 128)
        ((float4*)&Cs[0][0])[threadIdx.x] =
            ((const float4*)(Cm + (int64_t)(b * 2048 + lc * 32) * 16))[threadIdx.x];
    __syncthreads();
    for (int li = 0; li < 32; li++) {
        const int64_t rowz = (int64_t)(b * 2048 + lc * 32 + li);
        ushort4v xcv = *(const ushort4v*)&xc[rowz * 2048 + d0];
        ushort4v zv = *(const ushort4v*)&xz[rowz * 4096 + 2048 + d0];
        ushort4v o;
#pragma unroll
        for (int i = 0; i < 4; i++) {
            float s = Dv[i] * bf2f(xcv[i]);
#pragma unroll
            for (int n = 0; n < 16; n++) s += hreg[i][n] * Cs[li][n];
            o[i] = f2bf(s * silu_f(bf2f(zv[i])));
        }
        *(ushort4v*)&xz[rowz * 4096 + d0] = o;
    }
}

extern "C" void kernel_launch(void* const* d_in, const int* in_sizes, int n_in,
                              void* d_out, int out_size, void* d_ws, size_t ws_size,
                              hipStream_t stream) {
    (void)in_sizes; (void)n_in; (void)out_size; (void)ws_size;
    const float* x      = (const float*)d_in[0];
    const float* W_in   = (const float*)d_in[1];
    const float* conv_w = (const float*)d_in[2];
    const float* conv_b = (const float*)d_in[3];
    const float* W_xp   = (const float*)d_in[4];
    const float* Dp     = (const float*)d_in[6];   // d_in[5] = A_log, unused by reference
    const float* W_out  = (const float*)d_in[7];
    float* out = (float*)d_out;
    char* ws = (char*)d_ws;

    u16*   x_bf   = (u16*)(ws);                   // 16,777,216 B (dead after GEMM1)
    float* spart  = (float*)(ws);                 // alias: 6,291,456
    float* dB     = (float*)(ws + 6291456);       // 524,288
    float* Cm     = (float*)(ws + 6815744);       // 524,288
    float* hp     = (float*)(ws + 7340032);       // 4,194,304
    float* h      = (float*)(ws + 11534336);      // 524,288
    u16*   Wt_in  = (u16*)(ws + 16777216);        // 8,388,608
    u16*   Wt_out = (u16*)(ws + 25165824);        // 4,194,304
    u16*   Wxt    = (u16*)(ws + 29360128);        // 196,608
    u16*   xz     = (u16*)(ws + 29556736);        // 67,108,864
    u16*   xcv    = (u16*)(ws + 96665600);        // 33,554,432  (total ~130 MB)

    cvt_bf16_k<<<8192, 256, 0, stream>>>(x, x_bf, 2097152);
    trans_cvt_k<<<dim3(128, 32), 256, 0, stream>>>(W_in, Wt_in, 1024, 4096);
    trans_cvt_k<<<dim3(32, 64), 256, 0, stream>>>(W_out, Wt_out, 2048, 1024);
    prep_wxt_k<<<384, 256, 0, stream>>>(W_xp, Wxt);
    // xz = x @ W_in : M=8192 N=4096 K=1024; grid (8192/256)*(4096/128)=1024
    gemm_bt2<true><<<1024, 512, 0, stream>>>(x_bf, Wt_in, xz, 32, 16, 1024, 4096, 1024);
    conv_silu_k<<<2048, 256, 0, stream>>>(xz, conv_w, conv_b, xcv);
    ssm_proj_k<<<512, 256, 0, stream>>>(xcv, Wxt, spart);
    ssm_fin_k<<<32, 256, 0, stream>>>(spart, dB, Cm);
    h_part_k<<<256, 256, 0, stream>>>(xcv, dB, hp);
    h_red_k<<<512, 256, 0, stream>>>(hp, h);
    y_gate_k<<<512, 256, 0, stream>>>(xz, xcv, h, Cm, Dp);
    // out = y @ W_out : M=8192 N=1024 K=2048; grid (8192/256)*(1024/128)=256
    gemm_bt2<false><<<256, 512, 0, stream>>>(xz, Wt_out, out, 8, 32, 4096, 1024, 2048);
}

// Round 3
// 250.652 us; speedup vs baseline: 1.1283x; 1.1271x over previous
//
#include <hip/hip_runtime.h>
#include <hip/hip_bf16.h>
#include <stdint.h>

typedef __bf16 bf16x8 __attribute__((ext_vector_type(8)));
typedef float f32x4 __attribute__((ext_vector_type(4)));
typedef unsigned short u16;
typedef u16 ushort4v __attribute__((ext_vector_type(4)));
typedef u16 ushort8v __attribute__((ext_vector_type(8)));

__device__ __forceinline__ u16 f2bf(float f) {
    union { float f; uint32_t u; } v; v.f = f;
    uint32_t u = v.u + 0x7FFFu + ((v.u >> 16) & 1u);
    return (u16)(u >> 16);
}
__device__ __forceinline__ float bf2f(u16 b) {
    union { uint32_t u; float f; } v; v.u = ((uint32_t)b) << 16;
    return v.f;
}
__device__ __forceinline__ float silu_f(float v) {
    return v / (1.0f + __expf(-v));
}
__device__ __forceinline__ void gload_lds16(const u16* g, u16* l) {
    __builtin_amdgcn_global_load_lds(
        (const __attribute__((address_space(1))) void*)g,
        (__attribute__((address_space(3))) void*)l, 16, 0, 0);
}

// ---------------- prep kernels ----------------
__global__ void cvt_bf16_k(const float* __restrict__ src, u16* __restrict__ dst, int n4) {
    int i = blockIdx.x * 256 + threadIdx.x;
    if (i < n4) {
        float4 v = *(const float4*)&src[(int64_t)i * 4];
        ushort4v o = { f2bf(v.x), f2bf(v.y), f2bf(v.z), f2bf(v.w) };
        *(ushort4v*)&dst[(int64_t)i * 4] = o;
    }
}

// dst[c][r] = bf16(src[r][c]); R,C multiples of 32
__global__ __launch_bounds__(256) void trans_cvt_k(
        const float* __restrict__ src, u16* __restrict__ dst, int R, int C) {
    __shared__ float t[32][33];
    const int bc = blockIdx.x, br = blockIdx.y;
    const int tx = threadIdx.x & 31, ty = threadIdx.x >> 5;
#pragma unroll
    for (int i = 0; i < 4; i++) {
        int r = ty + i * 8;
        t[r][tx] = src[(int64_t)(br * 32 + r) * C + bc * 32 + tx];
    }
    __syncthreads();
#pragma unroll
    for (int i = 0; i < 4; i++) {
        int c = ty + i * 8;
        dst[(int64_t)(bc * 32 + c) * R + br * 32 + tx] = f2bf(t[tx][c]);
    }
}

// W_xproj (2048x33) -> Wxt (48x2048) bf16, rows 33..47 zero
__global__ void prep_wxt_k(const float* __restrict__ wx, u16* __restrict__ wxt) {
    int idx = blockIdx.x * 256 + threadIdx.x;
    if (idx < 48 * 2048) {
        int j = idx >> 11, d = idx & 2047;
        wxt[idx] = (j < 33) ? f2bf(wx[d * 33 + j]) : (u16)0;
    }
}

// =======================================================================
// Deep-pipelined MFMA GEMM, C = A * Bt^T  (8-phase / 4-phase template)
// BM=256 always. M_REP: per-wave 16-row fragments (8 -> wave 128 rows,
// 2Mx4N waves, BN=256; 4 -> wave 64 rows, 4Mx2N waves, BN=128).
// BK=64, 2 K-tiles per iteration, M_REP phases per iteration.
// Per phase: {ds_read regs | stage half-tile} -> barrier -> lgkmcnt(0)
//   -> setprio(1) 16 MFMA setprio(0) -> [counted vmcnt at tile end] -> barrier
// Half-tile lifetimes (verified): every stage targets a slot whose last
// reader finished >=1 barrier earlier; every staged half has >=3 phases
// before its consuming vmcnt-wait.
// =======================================================================
template<int M_REP, int WARPS_M, int B_HALVES, bool OUT_BF16>
__global__ __launch_bounds__(512) void gemm_dp(
        const u16* __restrict__ A, const u16* __restrict__ Bt,
        void* __restrict__ Cout, int nbn_sh, int NT, int lda, int ldb, int ldc) {
    constexpr int WARPS_N = 8 / WARPS_M;
    constexpr int QPT = M_REP / 2;            // phases per K-tile
    constexpr int WV_M = M_REP * 16;          // per-wave rows
    constexpr int BN = WARPS_N * 64;
    constexpr int B_T = BN * 64;              // u16 per B K-tile buffer

    __shared__ __align__(16) u16 As[2 * 16384];
    __shared__ __align__(16) u16 Bs[2 * B_T];

    const int tid = threadIdx.x;
    const int wave = tid >> 6;
    const int lane = tid & 63;
    const int wm = wave / WARPS_N, wn = wave % WARPS_N;
    const int fr = lane & 15, fq = lane >> 4;

    // T1 bijective XCD swizzle (gridDim.x % 8 == 0 at both call sites)
    const int nwg = gridDim.x;
    const int cpx = nwg >> 3;
    const int swz = (blockIdx.x & 7) * cpx + (blockIdx.x >> 3);
    const int bm = swz >> nbn_sh;
    const int bn = swz & ((1 << nbn_sh) - 1);

    // stage side: linear LDS dest, inverse-swizzled global source (rule #21)
    const int srow = tid >> 3;
    const int scol8 = ((tid & 7) ^ (srow & 7)) * 8;
    const u16* gA = A + (int64_t)(bm * 256 + srow) * lda + scol8;
    const u16* gB = Bt + (int64_t)(bn * BN + srow) * ldb + scol8;
    const int64_t lda64 = lda, ldb64 = ldb;

    // read side (swizzled): row*64 + ((kk*4+fq)^(fr&7))*8
    const int ksw0 = ((fq) ^ (fr & 7)) * 8;
    const int ksw1 = ((4 + fq) ^ (fr & 7)) * 8;
    const int arow0 = (wm * WV_M + fr) * 64;
    const int brow0 = (wn * 64 + fr) * 64;

    auto STAGE_A = [&](int kt, int buf) {   // both halves, 4 loads/thread
#pragma unroll
        for (int h = 0; h < 2; ++h)
#pragma unroll
            for (int j = 0; j < 2; ++j)
                gload_lds16(gA + (int64_t)(h * 128 + j * 64) * lda64 + kt * 64,
                            &As[buf * 16384 + h * 8192 + j * 4096 + tid * 8]);
    };
    auto STAGE_B_HALF = [&](int kt, int buf, int h) {  // 2 loads/thread
#pragma unroll
        for (int j = 0; j < 2; ++j)
            gload_lds16(gB + (int64_t)(h * 128 + j * 64) * ldb64 + kt * 64,
                        &Bs[buf * B_T + h * 8192 + j * 4096 + tid * 8]);
    };

    f32x4 acc[M_REP][4] = {};

    // ---- prologue: A(0), B(0) -> buf0; B(1) -> buf1 ----
    STAGE_A(0, 0);
#pragma unroll
    for (int h = 0; h < B_HALVES; ++h) STAGE_B_HALF(0, 0, h);
#pragma unroll
    for (int h = 0; h < B_HALVES; ++h) STAGE_B_HALF(1, 1, h);
    if constexpr (B_HALVES == 2) { asm volatile("s_waitcnt vmcnt(4)" ::: "memory"); }
    else                         { asm volatile("s_waitcnt vmcnt(2)" ::: "memory"); }
    __builtin_amdgcn_s_barrier();

    const int NI = NT >> 1;
    for (int s = 0; s < NI; ++s) {
        const bool more = (s + 1 < NI);
        const int kt2 = 2 * s + 2, kt3 = 2 * s + 3;
#pragma unroll
        for (int t = 0; t < 2; ++t) {
            const u16* Ab = &As[t * 16384];
            const u16* Bb = &Bs[t * B_T];
            bf16x8 breg[4][2];
#pragma unroll
            for (int q = 0; q < QPT; ++q) {
                if (q == 0) {
#pragma unroll
                    for (int n = 0; n < 4; ++n) {
                        breg[n][0] = *(const bf16x8*)(Bb + brow0 + n * 1024 + ksw0);
                        breg[n][1] = *(const bf16x8*)(Bb + brow0 + n * 1024 + ksw1);
                    }
                }
                bf16x8 areg[2][2];
#pragma unroll
                for (int j = 0; j < 2; ++j) {
                    areg[j][0] = *(const bf16x8*)(Ab + arow0 + (2 * q + j) * 1024 + ksw0);
                    areg[j][1] = *(const bf16x8*)(Ab + arow0 + (2 * q + j) * 1024 + ksw1);
                }
                // staging schedule (slot freed >=1 phase before; >=3 phases
                // to consuming wait)
                if constexpr (QPT == 4) {
                    if (t == 0 && q == 0)         STAGE_A(2 * s + 1, 1);
                    if (t == 0 && q == 2 && more) STAGE_B_HALF(kt2, 0, 0);
                    if (t == 0 && q == 3 && more) STAGE_B_HALF(kt2, 0, 1);
                    if (t == 1 && q == 0 && more) STAGE_A(kt2, 0);
                    if (t == 1 && q == 2 && more) STAGE_B_HALF(kt3, 1, 0);
                    if (t == 1 && q == 3 && more) STAGE_B_HALF(kt3, 1, 1);
                } else {
                    if (t == 0 && q == 0)         STAGE_A(2 * s + 1, 1);
                    if (t == 0 && q == 1 && more) STAGE_B_HALF(kt2, 0, 0);
                    if (t == 1 && q == 0 && more) STAGE_A(kt2, 0);
                    if (t == 1 && q == 1 && more) STAGE_B_HALF(kt3, 1, 0);
                }
                __builtin_amdgcn_s_barrier();
                asm volatile("s_waitcnt lgkmcnt(0)" ::: "memory");
                __builtin_amdgcn_sched_barrier(0);
                __builtin_amdgcn_s_setprio(1);
#pragma unroll
                for (int j = 0; j < 2; ++j)
#pragma unroll
                    for (int n = 0; n < 4; ++n) {
                        acc[2 * q + j][n] = __builtin_amdgcn_mfma_f32_16x16x32_bf16(
                            areg[j][0], breg[n][0], acc[2 * q + j][n], 0, 0, 0);
                        acc[2 * q + j][n] = __builtin_amdgcn_mfma_f32_16x16x32_bf16(
                            areg[j][1], breg[n][1], acc[2 * q + j][n], 0, 0, 0);
                    }
                __builtin_amdgcn_s_setprio(0);
                __builtin_amdgcn_sched_barrier(0);
                if (q == QPT - 1) {   // counted waits only at K-tile ends
                    if (more) {
                        if constexpr (B_HALVES == 2) { asm volatile("s_waitcnt vmcnt(4)" ::: "memory"); }
                        else                         { asm volatile("s_waitcnt vmcnt(2)" ::: "memory"); }
                    } else {
                        asm volatile("s_waitcnt vmcnt(0)" ::: "memory");
                    }
                }
                __builtin_amdgcn_s_barrier();
            }
        }
    }

    // ---- epilogue ----
#pragma unroll
    for (int m = 0; m < M_REP; ++m) {
#pragma unroll
        for (int n = 0; n < 4; ++n) {
            const int col = bn * BN + wn * 64 + n * 16 + fr;
#pragma unroll
            for (int r = 0; r < 4; ++r) {
                const int row = bm * 256 + wm * WV_M + m * 16 + fq * 4 + r;
                if constexpr (OUT_BF16)
                    ((u16*)Cout)[(int64_t)row * ldc + col] = f2bf(acc[m][n][r]);
                else
                    ((float*)Cout)[(int64_t)row * ldc + col] = acc[m][n][r];
            }
        }
    }
}

// ---------------- depthwise conv(4) + bias + SiLU ----------------
__global__ __launch_bounds__(256) void conv_silu_k(
        const u16* __restrict__ xz, const float* __restrict__ cw,
        const float* __restrict__ cb, u16* __restrict__ xc) {
    const int blk = blockIdx.x;
    const int b = blk >> 9;
    const int l0 = (blk & 511) << 2;
    const int d0 = threadIdx.x * 8;
    float w[8][4], bias[8];
#pragma unroll
    for (int j = 0; j < 8; j++) {
        float4 wv = *(const float4*)&cw[(d0 + j) * 4];
        w[j][0] = wv.x; w[j][1] = wv.y; w[j][2] = wv.z; w[j][3] = wv.w;
        bias[j] = cb[d0 + j];
    }
    float xp[7][8];
#pragma unroll
    for (int r = 0; r < 7; r++) {
        int l = l0 - 3 + r;
        if (l < 0) {
#pragma unroll
            for (int j = 0; j < 8; j++) xp[r][j] = 0.f;
        } else {
            ushort8v v = *(const ushort8v*)&xz[((int64_t)(b * 2048 + l)) * 4096 + d0];
#pragma unroll
            for (int j = 0; j < 8; j++) xp[r][j] = bf2f(v[j]);
        }
    }
#pragma unroll
    for (int li = 0; li < 4; li++) {
        ushort8v o;
#pragma unroll
        for (int j = 0; j < 8; j++) {
            float s = bias[j];
#pragma unroll
            for (int k = 0; k < 4; k++) s += w[j][k] * xp[li + k][j];
            o[j] = f2bf(silu_f(s));
        }
        *(ushort8v*)&xc[((int64_t)(b * 2048 + l0 + li)) * 2048 + d0] = o;
    }
}

// ---------------- ssm projection (K split by 4), spart: [4][8192][48] ----------------
__global__ __launch_bounds__(256) void ssm_proj_k(
        const u16* __restrict__ xc, const u16* __restrict__ wxt,
        float* __restrict__ spart) {
    const int gw = (blockIdx.x << 2) + (threadIdx.x >> 6);
    const int lane = threadIdx.x & 63;
    const int rb = gw >> 2, kc = gw & 3;
    const int fr = lane & 15, fq = lane >> 4;
    const u16* ap = xc + (int64_t)(rb * 16 + fr) * 2048 + kc * 512 + fq * 8;
    const u16* bp = wxt + (int64_t)fr * 2048 + kc * 512 + fq * 8;
    f32x4 acc0 = {}, acc1 = {}, acc2 = {};
#pragma unroll 4
    for (int k = 0; k < 512; k += 32) {
        bf16x8 av = *(const bf16x8*)(ap + k);
        bf16x8 b0 = *(const bf16x8*)(bp + k);
        bf16x8 b1 = *(const bf16x8*)(bp + 16 * 2048 + k);
        bf16x8 b2 = *(const bf16x8*)(bp + 32 * 2048 + k);
        acc0 = __builtin_amdgcn_mfma_f32_16x16x32_bf16(av, b0, acc0, 0, 0, 0);
        acc1 = __builtin_amdgcn_mfma_f32_16x16x32_bf16(av, b1, acc1, 0, 0, 0);
        acc2 = __builtin_amdgcn_mfma_f32_16x16x32_bf16(av, b2, acc2, 0, 0, 0);
    }
    float* sp = spart + ((int64_t)kc * 8192 + rb * 16) * 48;
#pragma unroll
    for (int r = 0; r < 4; r++) {
        int ro = (fq * 4 + r) * 48;
        sp[ro + fr] = acc0[r];
        sp[ro + 16 + fr] = acc1[r];
        sp[ro + 32 + fr] = acc2[r];
    }
}

__global__ __launch_bounds__(256) void ssm_fin_k(
        const float* __restrict__ spart, float* __restrict__ dB,
        float* __restrict__ Cm) {
    const int row = blockIdx.x * 256 + threadIdx.x;
    const float* sp = spart + (int64_t)row * 48;
    float s[33];
#pragma unroll
    for (int j = 0; j < 33; j++)
        s[j] = sp[j] + sp[8192 * 48 + j] + sp[2 * 8192 * 48 + j] + sp[3 * 8192 * 48 + j];
    float d0v = s[0];
    float delta = (d0v > 20.f) ? d0v : log1pf(__expf(d0v));
#pragma unroll
    for (int n = 0; n < 16; n++) {
        dB[(int64_t)row * 16 + n] = delta * s[1 + n] * (1.0f / 2048.0f);
        Cm[(int64_t)row * 16 + n] = s[17 + n];
    }
}

__global__ __launch_bounds__(256) void h_part_k(
        const u16* __restrict__ xc, const float* __restrict__ dB,
        float* __restrict__ hp) {
    const int blk = blockIdx.x;
    const int dt = blk & 7, b = (blk >> 3) & 3, lc = blk >> 5;
    const int d = dt * 256 + threadIdx.x;
    const u16* xp = xc + ((int64_t)(b * 2048 + lc * 256)) * 2048 + d;
    const float* dbp = dB + (int64_t)(b * 2048 + lc * 256) * 16;
    float acc[16] = {};
    for (int l = 0; l < 256; l++) {
        float xv = bf2f(xp[(int64_t)l * 2048]);
#pragma unroll
        for (int n = 0; n < 16; n++) acc[n] += xv * dbp[l * 16 + n];
    }
    float* o = hp + ((int64_t)((lc * 4 + b) * 2048 + d)) * 16;
#pragma unroll
    for (int n = 0; n < 16; n++) o[n] = acc[n];
}

__global__ void h_red_k(const float* __restrict__ hp, float* __restrict__ h) {
    const int i = blockIdx.x * 256 + threadIdx.x;  // < 131072
    float s = 0.f;
#pragma unroll
    for (int c = 0; c < 8; c++) s += hp[(int64_t)c * 131072 + i];
    h[i] = s;
}

__global__ __launch_bounds__(256) void y_gate_k(
        u16* __restrict__ xz, const u16* __restrict__ xc,
        const float* __restrict__ h, const float* __restrict__ Cm,
        const float* __restrict__ Dp) {
    const int blk = blockIdx.x;
    const int lc = blk & 63, dt = (blk >> 6) & 1, b = blk >> 7;
    const int d0 = dt * 1024 + threadIdx.x * 4;
    const float* hpp = h + ((int64_t)(b * 2048 + d0)) * 16;
    float hreg[4][16];
#pragma unroll
    for (int i = 0; i < 4; i++)
#pragma unroll
        for (int n = 0; n < 16; n++) hreg[i][n] = hpp[i * 16 + n];
    float Dv[4];
#pragma unroll
    for (int i = 0; i < 4; i++) Dv[i] = Dp[d0 + i];
    __shared__ float Cs[32][16];
    if (threadIdx.x < 128)
        ((float4*)&Cs[0][0])[threadIdx.x] =
            ((const float4*)(Cm + (int64_t)(b * 2048 + lc * 32) * 16))[threadIdx.x];
    __syncthreads();
    for (int li = 0; li < 32; li++) {
        const int64_t rowz = (int64_t)(b * 2048 + lc * 32 + li);
        ushort4v xcv = *(const ushort4v*)&xc[rowz * 2048 + d0];
        ushort4v zv = *(const ushort4v*)&xz[rowz * 4096 + 2048 + d0];
        ushort4v o;
#pragma unroll
        for (int i = 0; i < 4; i++) {
            float s = Dv[i] * bf2f(xcv[i]);
#pragma unroll
            for (int n = 0; n < 16; n++) s += hreg[i][n] * Cs[li][n];
            o[i] = f2bf(s * silu_f(bf2f(zv[i])));
        }
        *(ushort4v*)&xz[rowz * 4096 + d0] = o;
    }
}

extern "C" void kernel_launch(void* const* d_in, const int* in_sizes, int n_in,
                              void* d_out, int out_size, void* d_ws, size_t ws_size,
                              hipStream_t stream) {
    (void)in_sizes; (void)n_in; (void)out_size; (void)ws_size;
    const float* x      = (const float*)d_in[0];
    const float* W_in   = (const float*)d_in[1];
    const float* conv_w = (const float*)d_in[2];
    const float* conv_b = (const float*)d_in[3];
    const float* W_xp   = (const float*)d_in[4];
    const float* Dp     = (const float*)d_in[6];   // d_in[5] = A_log, unused by reference
    const float* W_out  = (const float*)d_in[7];
    float* out = (float*)d_out;
    char* ws = (char*)d_ws;

    u16*   x_bf   = (u16*)(ws);                   // 16,777,216 B (dead after GEMM1)
    float* spart  = (float*)(ws);                 // alias: 6,291,456
    float* dB     = (float*)(ws + 6291456);       // 524,288
    float* Cm     = (float*)(ws + 6815744);       // 524,288
    float* hp     = (float*)(ws + 7340032);       // 4,194,304
    float* h      = (float*)(ws + 11534336);      // 524,288
    u16*   Wt_in  = (u16*)(ws + 16777216);        // 8,388,608
    u16*   Wt_out = (u16*)(ws + 25165824);        // 4,194,304
    u16*   Wxt    = (u16*)(ws + 29360128);        // 196,608
    u16*   xz     = (u16*)(ws + 29556736);        // 67,108,864
    u16*   xcv    = (u16*)(ws + 96665600);        // 33,554,432  (total ~130 MB)

    cvt_bf16_k<<<8192, 256, 0, stream>>>(x, x_bf, 2097152);
    trans_cvt_k<<<dim3(128, 32), 256, 0, stream>>>(W_in, Wt_in, 1024, 4096);
    trans_cvt_k<<<dim3(32, 64), 256, 0, stream>>>(W_out, Wt_out, 2048, 1024);
    prep_wxt_k<<<384, 256, 0, stream>>>(W_xp, Wxt);
    // xz = x @ W_in : M=8192 N=4096 K=1024; grid (8192/256)*(4096/256)=512
    gemm_dp<8, 2, 2, true><<<512, 512, 0, stream>>>(x_bf, Wt_in, xz, 4, 16, 1024, 1024, 4096);
    conv_silu_k<<<2048, 256, 0, stream>>>(xz, conv_w, conv_b, xcv);
    ssm_proj_k<<<512, 256, 0, stream>>>(xcv, Wxt, spart);
    ssm_fin_k<<<32, 256, 0, stream>>>(spart, dB, Cm);
    h_part_k<<<256, 256, 0, stream>>>(xcv, dB, hp);
    h_red_k<<<512, 256, 0, stream>>>(hp, h);
    y_gate_k<<<512, 256, 0, stream>>>(xz, xcv, h, Cm, Dp);
    // out = y @ W_out : M=8192 N=1024 K=2048; grid (8192/256)*(1024/128)=256
    gemm_dp<4, 4, 1, false><<<256, 512, 0, stream>>>(xz, Wt_out, out, 3, 32, 4096, 2048, 1024);
}

// Round 4
// 244.127 us; speedup vs baseline: 1.1584x; 1.0267x over previous
//
#include <hip/hip_runtime.h>
#include <hip/hip_bf16.h>
#include <stdint.h>

typedef __bf16 bf16x8 __attribute__((ext_vector_type(8)));
typedef float f32x4 __attribute__((ext_vector_type(4)));
typedef unsigned short u16;
typedef u16 ushort4v __attribute__((ext_vector_type(4)));
typedef u16 ushort8v __attribute__((ext_vector_type(8)));

__device__ __forceinline__ u16 f2bf(float f) {
    union { float f; uint32_t u; } v; v.f = f;
    uint32_t u = v.u + 0x7FFFu + ((v.u >> 16) & 1u);
    return (u16)(u >> 16);
}
__device__ __forceinline__ float bf2f(u16 b) {
    union { uint32_t u; float f; } v; v.u = ((uint32_t)b) << 16;
    return v.f;
}
__device__ __forceinline__ float silu_f(float v) {
    return v / (1.0f + __expf(-v));
}
__device__ __forceinline__ void gload_lds16(const u16* g, u16* l) {
    __builtin_amdgcn_global_load_lds(
        (const __attribute__((address_space(1))) void*)g,
        (__attribute__((address_space(3))) void*)l, 16, 0, 0);
}
// inline-asm LDS read: opaque to the backend's LDS-DMA alias tracking, so the
// hand-placed counted vmcnt is the ONLY wait (rule #18: needs lgkmcnt(0) +
// sched_barrier(0) before dependent MFMAs).
__device__ __forceinline__ bf16x8 lds_read16(uint32_t addr) {
    bf16x8 r;
    asm volatile("ds_read_b128 %0, %1" : "=v"(r) : "v"(addr));
    return r;
}

// ---------------- fused prep kernel (block-range dispatch) ----------------
__device__ __forceinline__ void trans_tile(
        const float* __restrict__ src, u16* __restrict__ dst, int R, int C,
        int bc, int br, float (*tt)[33], int tid) {
    const int tx = tid & 31, ty = tid >> 5;
#pragma unroll
    for (int i = 0; i < 4; i++)
        tt[ty + i * 8][tx] = src[(int64_t)(br * 32 + ty + i * 8) * C + bc * 32 + tx];
    __syncthreads();
#pragma unroll
    for (int i = 0; i < 4; i++)
        dst[(int64_t)(bc * 32 + ty + i * 8) * R + br * 32 + tx] = f2bf(tt[tx][ty + i * 8]);
}

__global__ __launch_bounds__(256) void prep_k(
        const float* __restrict__ x, u16* __restrict__ x_bf,
        const float* __restrict__ Wi, u16* __restrict__ Wti,
        const float* __restrict__ Wo, u16* __restrict__ Wto,
        const float* __restrict__ wx, u16* __restrict__ wxt) {
    __shared__ float tt[32][33];
    const int blk = blockIdx.x, tid = threadIdx.x;
    if (blk < 8192) {
        int i = blk * 256 + tid;   // exact: 8192*256 = 2,097,152 float4 quads
        float4 v = *(const float4*)&x[(int64_t)i * 4];
        ushort4v o = { f2bf(v.x), f2bf(v.y), f2bf(v.z), f2bf(v.w) };
        *(ushort4v*)&x_bf[(int64_t)i * 4] = o;
    } else if (blk < 12288) {
        int t = blk - 8192;        // W_in 1024x4096 -> Wt_in 4096x1024
        trans_tile(Wi, Wti, 1024, 4096, t & 127, t >> 7, tt, tid);
    } else if (blk < 14336) {
        int t = blk - 12288;       // W_out 2048x1024 -> Wt_out 1024x2048
        trans_tile(Wo, Wto, 2048, 1024, t & 31, t >> 5, tt, tid);
    } else {
        int idx = (blk - 14336) * 256 + tid;   // exact: 384*256 = 48*2048
        int j = idx >> 11, d = idx & 2047;
        wxt[idx] = (j < 33) ? f2bf(wx[d * 33 + j]) : (u16)0;
    }
}

// =======================================================================
// Deep-pipelined MFMA GEMM, C = A * Bt^T  (8-phase / 4-phase, asm ds_read)
// BM=256. M_REP=8: 2Mx4N waves, BN=256, per-wave 128x64 (GEMM1).
// M_REP=4: 4Mx2N waves, BN=128, per-wave 64x64 (GEMM3). BK=64, 2 K-tiles
// per iteration, QPT=M_REP/2 phases per K-tile. Exactly 2 global_load_lds
// per phase; counted vmcnt only at K-tile ends (never 0 mid-loop).
// In-flight table (steady state, GEMM1): enter iter: B(2s+1)x4.
//  t0 issues A(2s+1)x4 [q0,q1] + B(2s+2)x4 [q2,q3]; end-t0 vmcnt(4)
//    drains B(2s+1)+A(2s+1) (needed t1), leaves B(2s+2).
//  t1 issues A(2s+2)x4 + B(2s+3)x4; end-t1 vmcnt(4) drains
//    B(2s+2)+A(2s+2) (needed next t0), leaves B(2s+3). GEMM3: halve B.
// =======================================================================
template<int M_REP, int WARPS_M, int B_HALVES, bool OUT_BF16>
__global__ __launch_bounds__(512) void gemm_dp(
        const u16* __restrict__ A, const u16* __restrict__ Bt,
        void* __restrict__ Cout, int nbn_sh, int NT, int lda, int ldb, int ldc) {
    constexpr int WARPS_N = 8 / WARPS_M;
    constexpr int QPT = M_REP / 2;
    constexpr int WV_M = M_REP * 16;
    constexpr int BN = WARPS_N * 64;
    constexpr int B_T = BN * 64;              // u16 per B K-tile buffer

    __shared__ __align__(16) u16 As[2 * 16384];
    __shared__ __align__(16) u16 Bs[2 * B_T];
    const uint32_t asb = (uint32_t)(uintptr_t)&As[0];
    const uint32_t bsb = (uint32_t)(uintptr_t)&Bs[0];

    const int tid = threadIdx.x;
    const int wave = tid >> 6;
    const int lane = tid & 63;
    const int wm = wave / WARPS_N, wn = wave % WARPS_N;
    const int fr = lane & 15, fq = lane >> 4;

    // T1 bijective XCD swizzle (gridDim.x % 8 == 0 at both call sites)
    const int nwg = gridDim.x;
    const int cpx = nwg >> 3;
    const int swz = (blockIdx.x & 7) * cpx + (blockIdx.x >> 3);
    const int bm = swz >> nbn_sh;
    const int bn = swz & ((1 << nbn_sh) - 1);

    // stage side: linear LDS dest, inverse-swizzled global source (rule #21)
    const int srow = tid >> 3;
    const int scol8 = ((tid & 7) ^ (srow & 7)) * 8;
    const u16* gA = A + (int64_t)(bm * 256 + srow) * lda + scol8;
    const u16* gB = Bt + (int64_t)(bn * BN + srow) * ldb + scol8;
    const int64_t lda64 = lda, ldb64 = ldb;

    // read side (swizzled): byte addr = (row*64 + ((kk*4+fq)^(fr&7))*8)*2
    const int ksw0 = ((fq) ^ (fr & 7)) * 8;
    const int ksw1 = ((4 + fq) ^ (fr & 7)) * 8;
    const int arow0 = (wm * WV_M + fr) * 64;
    const int brow0 = (wn * 64 + fr) * 64;

    auto STAGE_A_HALF = [&](int kt, int buf, int h) {   // 2 loads
#pragma unroll
        for (int j = 0; j < 2; ++j)
            gload_lds16(gA + (int64_t)(h * 128 + j * 64) * lda64 + kt * 64,
                        &As[buf * 16384 + h * 8192 + j * 4096 + tid * 8]);
    };
    auto STAGE_B_HALF = [&](int kt, int buf, int h) {   // 2 loads
#pragma unroll
        for (int j = 0; j < 2; ++j)
            gload_lds16(gB + (int64_t)(h * 128 + j * 64) * ldb64 + kt * 64,
                        &Bs[buf * B_T + h * 8192 + j * 4096 + tid * 8]);
    };

    f32x4 acc[M_REP][4] = {};

    // ---- prologue: A(0),B(0) -> buf0; B(1) -> buf1 ----
    STAGE_A_HALF(0, 0, 0); STAGE_A_HALF(0, 0, 1);
#pragma unroll
    for (int h = 0; h < B_HALVES; ++h) STAGE_B_HALF(0, 0, h);
#pragma unroll
    for (int h = 0; h < B_HALVES; ++h) STAGE_B_HALF(1, 1, h);
    if constexpr (B_HALVES == 2) { asm volatile("s_waitcnt vmcnt(4)" ::: "memory"); }
    else                         { asm volatile("s_waitcnt vmcnt(2)" ::: "memory"); }
    __builtin_amdgcn_s_barrier();

    const int NI = NT >> 1;
    for (int s = 0; s < NI; ++s) {
        const bool more = (s + 1 < NI);
#pragma unroll
        for (int t = 0; t < 2; ++t) {
            const uint32_t Ab = asb + t * 32768u;
            const uint32_t Bb = bsb + t * (uint32_t)(B_T * 2);
            bf16x8 breg[4][2];
#pragma unroll
            for (int q = 0; q < QPT; ++q) {
                if (q == 0) {
#pragma unroll
                    for (int n = 0; n < 4; ++n) {
                        breg[n][0] = lds_read16(Bb + (uint32_t)(brow0 + n * 1024 + ksw0) * 2);
                        breg[n][1] = lds_read16(Bb + (uint32_t)(brow0 + n * 1024 + ksw1) * 2);
                    }
                }
                bf16x8 areg[2][2];
#pragma unroll
                for (int j = 0; j < 2; ++j) {
                    areg[j][0] = lds_read16(Ab + (uint32_t)(arow0 + (2 * q + j) * 1024 + ksw0) * 2);
                    areg[j][1] = lds_read16(Ab + (uint32_t)(arow0 + (2 * q + j) * 1024 + ksw1) * 2);
                }
                // staging: exactly 2 global_load_lds per phase
                if constexpr (QPT == 4) {
                    if (t == 0 && q == 0)         STAGE_A_HALF(2 * s + 1, 1, 0);
                    if (t == 0 && q == 1)         STAGE_A_HALF(2 * s + 1, 1, 1);
                    if (t == 0 && q == 2 && more) STAGE_B_HALF(2 * s + 2, 0, 0);
                    if (t == 0 && q == 3 && more) STAGE_B_HALF(2 * s + 2, 0, 1);
                    if (t == 1 && q == 0 && more) STAGE_A_HALF(2 * s + 2, 0, 0);
                    if (t == 1 && q == 1 && more) STAGE_A_HALF(2 * s + 2, 0, 1);
                    if (t == 1 && q == 2 && more) STAGE_B_HALF(2 * s + 3, 1, 0);
                    if (t == 1 && q == 3 && more) STAGE_B_HALF(2 * s + 3, 1, 1);
                } else {
                    if (t == 0 && q == 0)         STAGE_A_HALF(2 * s + 1, 1, 0);
                    if (t == 0 && q == 1) {       STAGE_A_HALF(2 * s + 1, 1, 1);
                        if (more)                 STAGE_B_HALF(2 * s + 2, 0, 0); }
                    if (t == 1 && q == 0 && more) STAGE_A_HALF(2 * s + 2, 0, 0);
                    if (t == 1 && q == 1 && more) { STAGE_A_HALF(2 * s + 2, 0, 1);
                                                    STAGE_B_HALF(2 * s + 3, 1, 0); }
                }
                __builtin_amdgcn_s_barrier();
                asm volatile("s_waitcnt lgkmcnt(0)" ::: "memory");
                __builtin_amdgcn_sched_barrier(0);
                __builtin_amdgcn_s_setprio(1);
#pragma unroll
                for (int j = 0; j < 2; ++j)
#pragma unroll
                    for (int n = 0; n < 4; ++n) {
                        acc[2 * q + j][n] = __builtin_amdgcn_mfma_f32_16x16x32_bf16(
                            areg[j][0], breg[n][0], acc[2 * q + j][n], 0, 0, 0);
                        acc[2 * q + j][n] = __builtin_amdgcn_mfma_f32_16x16x32_bf16(
                            areg[j][1], breg[n][1], acc[2 * q + j][n], 0, 0, 0);
                    }
                __builtin_amdgcn_s_setprio(0);
                __builtin_amdgcn_sched_barrier(0);
                if (q == QPT - 1) {   // counted waits only at K-tile ends
                    if (more) {
                        if constexpr (B_HALVES == 2) { asm volatile("s_waitcnt vmcnt(4)" ::: "memory"); }
                        else                         { asm volatile("s_waitcnt vmcnt(2)" ::: "memory"); }
                    } else {
                        asm volatile("s_waitcnt vmcnt(0)" ::: "memory");
                    }
                }
                __builtin_amdgcn_s_barrier();
            }
        }
    }

    // ---- epilogue ----
#pragma unroll
    for (int m = 0; m < M_REP; ++m) {
#pragma unroll
        for (int n = 0; n < 4; ++n) {
            const int col = bn * BN + wn * 64 + n * 16 + fr;
#pragma unroll
            for (int r = 0; r < 4; ++r) {
                const int row = bm * 256 + wm * WV_M + m * 16 + fq * 4 + r;
                if constexpr (OUT_BF16)
                    ((u16*)Cout)[(int64_t)row * ldc + col] = f2bf(acc[m][n][r]);
                else
                    ((float*)Cout)[(int64_t)row * ldc + col] = acc[m][n][r];
            }
        }
    }
}

// ---------------- depthwise conv(4) + bias + SiLU ----------------
__global__ __launch_bounds__(256) void conv_silu_k(
        const u16* __restrict__ xz, const float* __restrict__ cw,
        const float* __restrict__ cb, u16* __restrict__ xc) {
    const int blk = blockIdx.x;
    const int b = blk >> 9;
    const int l0 = (blk & 511) << 2;
    const int d0 = threadIdx.x * 8;
    float w[8][4], bias[8];
#pragma unroll
    for (int j = 0; j < 8; j++) {
        float4 wv = *(const float4*)&cw[(d0 + j) * 4];
        w[j][0] = wv.x; w[j][1] = wv.y; w[j][2] = wv.z; w[j][3] = wv.w;
        bias[j] = cb[d0 + j];
    }
    float xp[7][8];
#pragma unroll
    for (int r = 0; r < 7; r++) {
        int l = l0 - 3 + r;
        if (l < 0) {
#pragma unroll
            for (int j = 0; j < 8; j++) xp[r][j] = 0.f;
        } else {
            ushort8v v = *(const ushort8v*)&xz[((int64_t)(b * 2048 + l)) * 4096 + d0];
#pragma unroll
            for (int j = 0; j < 8; j++) xp[r][j] = bf2f(v[j]);
        }
    }
#pragma unroll
    for (int li = 0; li < 4; li++) {
        ushort8v o;
#pragma unroll
        for (int j = 0; j < 8; j++) {
            float s = bias[j];
#pragma unroll
            for (int k = 0; k < 4; k++) s += w[j][k] * xp[li + k][j];
            o[j] = f2bf(silu_f(s));
        }
        *(ushort8v*)&xc[((int64_t)(b * 2048 + l0 + li)) * 2048 + d0] = o;
    }
}

// ---------------- ssm projection (K split by 4), spart: [4][8192][48] ----------------
__global__ __launch_bounds__(256) void ssm_proj_k(
        const u16* __restrict__ xc, const u16* __restrict__ wxt,
        float* __restrict__ spart) {
    const int gw = (blockIdx.x << 2) + (threadIdx.x >> 6);
    const int lane = threadIdx.x & 63;
    const int rb = gw >> 2, kc = gw & 3;
    const int fr = lane & 15, fq = lane >> 4;
    const u16* ap = xc + (int64_t)(rb * 16 + fr) * 2048 + kc * 512 + fq * 8;
    const u16* bp = wxt + (int64_t)fr * 2048 + kc * 512 + fq * 8;
    f32x4 acc0 = {}, acc1 = {}, acc2 = {};
#pragma unroll 4
    for (int k = 0; k < 512; k += 32) {
        bf16x8 av = *(const bf16x8*)(ap + k);
        bf16x8 b0 = *(const bf16x8*)(bp + k);
        bf16x8 b1 = *(const bf16x8*)(bp + 16 * 2048 + k);
        bf16x8 b2 = *(const bf16x8*)(bp + 32 * 2048 + k);
        acc0 = __builtin_amdgcn_mfma_f32_16x16x32_bf16(av, b0, acc0, 0, 0, 0);
        acc1 = __builtin_amdgcn_mfma_f32_16x16x32_bf16(av, b1, acc1, 0, 0, 0);
        acc2 = __builtin_amdgcn_mfma_f32_16x16x32_bf16(av, b2, acc2, 0, 0, 0);
    }
    float* sp = spart + ((int64_t)kc * 8192 + rb * 16) * 48;
#pragma unroll
    for (int r = 0; r < 4; r++) {
        int ro = (fq * 4 + r) * 48;
        sp[ro + fr] = acc0[r];
        sp[ro + 16 + fr] = acc1[r];
        sp[ro + 32 + fr] = acc2[r];
    }
}

__global__ __launch_bounds__(256) void ssm_fin_k(
        const float* __restrict__ spart, float* __restrict__ dB,
        float* __restrict__ Cm) {
    const int row = blockIdx.x * 256 + threadIdx.x;
    const float* sp = spart + (int64_t)row * 48;
    float s[33];
#pragma unroll
    for (int j = 0; j < 33; j++)
        s[j] = sp[j] + sp[8192 * 48 + j] + sp[2 * 8192 * 48 + j] + sp[3 * 8192 * 48 + j];
    float d0v = s[0];
    float delta = (d0v > 20.f) ? d0v : log1pf(__expf(d0v));
#pragma unroll
    for (int n = 0; n < 16; n++) {
        dB[(int64_t)row * 16 + n] = delta * s[1 + n] * (1.0f / 2048.0f);
        Cm[(int64_t)row * 16 + n] = s[17 + n];
    }
}

__global__ __launch_bounds__(256) void h_part_k(
        const u16* __restrict__ xc, const float* __restrict__ dB,
        float* __restrict__ hp) {
    const int blk = blockIdx.x;
    const int dt = blk & 7, b = (blk >> 3) & 3, lc = blk >> 5;
    const int d = dt * 256 + threadIdx.x;
    const u16* xp = xc + ((int64_t)(b * 2048 + lc * 256)) * 2048 + d;
    const float* dbp = dB + (int64_t)(b * 2048 + lc * 256) * 16;
    float acc[16] = {};
    for (int l = 0; l < 256; l++) {
        float xv = bf2f(xp[(int64_t)l * 2048]);
#pragma unroll
        for (int n = 0; n < 16; n++) acc[n] += xv * dbp[l * 16 + n];
    }
    float* o = hp + ((int64_t)((lc * 4 + b) * 2048 + d)) * 16;
#pragma unroll
    for (int n = 0; n < 16; n++) o[n] = acc[n];
}

__global__ void h_red_k(const float* __restrict__ hp, float* __restrict__ h) {
    const int i = blockIdx.x * 256 + threadIdx.x;  // < 131072
    float s = 0.f;
#pragma unroll
    for (int c = 0; c < 8; c++) s += hp[(int64_t)c * 131072 + i];
    h[i] = s;
}

__global__ __launch_bounds__(256) void y_gate_k(
        u16* __restrict__ xz, const u16* __restrict__ xc,
        const float* __restrict__ h, const float* __restrict__ Cm,
        const float* __restrict__ Dp) {
    const int blk = blockIdx.x;
    const int lc = blk & 63, dt = (blk >> 6) & 1, b = blk >> 7;
    const int d0 = dt * 1024 + threadIdx.x * 4;
    const float* hpp = h + ((int64_t)(b * 2048 + d0)) * 16;
    float hreg[4][16];
#pragma unroll
    for (int i = 0; i < 4; i++)
#pragma unroll
        for (int n = 0; n < 16; n++) hreg[i][n] = hpp[i * 16 + n];
    float Dv[4];
#pragma unroll
    for (int i = 0; i < 4; i++) Dv[i] = Dp[d0 + i];
    __shared__ float Cs[32][16];
    if (threadIdx.x < 128)
        ((float4*)&Cs[0][0])[threadIdx.x] =
            ((const float4*)(Cm + (int64_t)(b * 2048 + lc * 32) * 16))[threadIdx.x];
    __syncthreads();
    for (int li = 0; li < 32; li++) {
        const int64_t rowz = (int64_t)(b * 2048 + lc * 32 + li);
        ushort4v xcv = *(const ushort4v*)&xc[rowz * 2048 + d0];
        ushort4v zv = *(const ushort4v*)&xz[rowz * 4096 + 2048 + d0];
        ushort4v o;
#pragma unroll
        for (int i = 0; i < 4; i++) {
            float s = Dv[i] * bf2f(xcv[i]);
#pragma unroll
            for (int n = 0; n < 16; n++) s += hreg[i][n] * Cs[li][n];
            o[i] = f2bf(s * silu_f(bf2f(zv[i])));
        }
        *(ushort4v*)&xz[rowz * 4096 + d0] = o;
    }
}

extern "C" void kernel_launch(void* const* d_in, const int* in_sizes, int n_in,
                              void* d_out, int out_size, void* d_ws, size_t ws_size,
                              hipStream_t stream) {
    (void)in_sizes; (void)n_in; (void)out_size; (void)ws_size;
    const float* x      = (const float*)d_in[0];
    const float* W_in   = (const float*)d_in[1];
    const float* conv_w = (const float*)d_in[2];
    const float* conv_b = (const float*)d_in[3];
    const float* W_xp   = (const float*)d_in[4];
    const float* Dp     = (const float*)d_in[6];   // d_in[5] = A_log, unused by reference
    const float* W_out  = (const float*)d_in[7];
    float* out = (float*)d_out;
    char* ws = (char*)d_ws;

    u16*   x_bf   = (u16*)(ws);                   // 16,777,216 B (dead after GEMM1)
    float* spart  = (float*)(ws);                 // alias: 6,291,456
    float* dB     = (float*)(ws + 6291456);       // 524,288
    float* Cm     = (float*)(ws + 6815744);       // 524,288
    float* hp     = (float*)(ws + 7340032);       // 4,194,304
    float* h      = (float*)(ws + 11534336);      // 524,288
    u16*   Wt_in  = (u16*)(ws + 16777216);        // 8,388,608
    u16*   Wt_out = (u16*)(ws + 25165824);        // 4,194,304
    u16*   Wxt    = (u16*)(ws + 29360128);        // 196,608
    u16*   xz     = (u16*)(ws + 29556736);        // 67,108,864
    u16*   xcv    = (u16*)(ws + 96665600);        // 33,554,432  (total ~130 MB)

    prep_k<<<14720, 256, 0, stream>>>(x, x_bf, W_in, Wt_in, W_out, Wt_out, W_xp, Wxt);
    // xz = x @ W_in : M=8192 N=4096 K=1024; grid (8192/256)*(4096/256)=512
    gemm_dp<8, 2, 2, true><<<512, 512, 0, stream>>>(x_bf, Wt_in, xz, 4, 16, 1024, 1024, 4096);
    conv_silu_k<<<2048, 256, 0, stream>>>(xz, conv_w, conv_b, xcv);
    ssm_proj_k<<<512, 256, 0, stream>>>(xcv, Wxt, spart);
    ssm_fin_k<<<32, 256, 0, stream>>>(spart, dB, Cm);
    h_part_k<<<256, 256, 0, stream>>>(xcv, dB, hp);
    h_red_k<<<512, 256, 0, stream>>>(hp, h);
    y_gate_k<<<512, 256, 0, stream>>>(xz, xcv, h, Cm, Dp);
    // out = y @ W_out : M=8192 N=1024 K=2048; grid (8192/256)*(1024/128)=256
    gemm_dp<4, 4, 1, false><<<256, 512, 0, stream>>>(xz, Wt_out, out, 3, 32, 4096, 2048, 1024);
}

// Round 5
// 241.629 us; speedup vs baseline: 1.1704x; 1.0103x over previous
//
#include <hip/hip_runtime.h>
#include <hip/hip_bf16.h>
#include <stdint.h>

typedef __bf16 bf16x8 __attribute__((ext_vector_type(8)));
typedef float f32x4 __attribute__((ext_vector_type(4)));
typedef unsigned short u16;
typedef u16 ushort4v __attribute__((ext_vector_type(4)));
typedef u16 ushort8v __attribute__((ext_vector_type(8)));

__device__ __forceinline__ u16 f2bf(float f) {
    union { float f; uint32_t u; } v; v.f = f;
    uint32_t u = v.u + 0x7FFFu + ((v.u >> 16) & 1u);
    return (u16)(u >> 16);
}
__device__ __forceinline__ float bf2f(u16 b) {
    union { uint32_t u; float f; } v; v.u = ((uint32_t)b) << 16;
    return v.f;
}
__device__ __forceinline__ float silu_f(float v) {
    return v / (1.0f + __expf(-v));
}
__device__ __forceinline__ void gload_lds16(const u16* g, u16* l) {
    __builtin_amdgcn_global_load_lds(
        (const __attribute__((address_space(1))) void*)g,
        (__attribute__((address_space(3))) void*)l, 16, 0, 0);
}

// ---------------- fused prep kernel (block-range dispatch) ----------------
__device__ __forceinline__ void trans_tile(
        const float* __restrict__ src, u16* __restrict__ dst, int R, int C,
        int bc, int br, float (*tt)[33], int tid) {
    const int tx = tid & 31, ty = tid >> 5;
#pragma unroll
    for (int i = 0; i < 4; i++)
        tt[ty + i * 8][tx] = src[(int64_t)(br * 32 + ty + i * 8) * C + bc * 32 + tx];
    __syncthreads();
#pragma unroll
    for (int i = 0; i < 4; i++)
        dst[(int64_t)(bc * 32 + ty + i * 8) * R + br * 32 + tx] = f2bf(tt[tx][ty + i * 8]);
}

__global__ __launch_bounds__(256) void prep_k(
        const float* __restrict__ x, u16* __restrict__ x_bf,
        const float* __restrict__ Wi, u16* __restrict__ Wti,
        const float* __restrict__ Wo, u16* __restrict__ Wto,
        const float* __restrict__ wx, u16* __restrict__ wxt) {
    __shared__ float tt[32][33];
    const int blk = blockIdx.x, tid = threadIdx.x;
    if (blk < 8192) {
        int i = blk * 256 + tid;
        float4 v = *(const float4*)&x[(int64_t)i * 4];
        ushort4v o = { f2bf(v.x), f2bf(v.y), f2bf(v.z), f2bf(v.w) };
        *(ushort4v*)&x_bf[(int64_t)i * 4] = o;
    } else if (blk < 12288) {
        int t = blk - 8192;        // W_in 1024x4096 -> Wt_in 4096x1024
        trans_tile(Wi, Wti, 1024, 4096, t & 127, t >> 7, tt, tid);
    } else if (blk < 14336) {
        int t = blk - 12288;       // W_out 2048x1024 -> Wt_out 1024x2048
        trans_tile(Wo, Wto, 2048, 1024, t & 31, t >> 5, tt, tid);
    } else {
        int idx = (blk - 14336) * 256 + tid;
        int j = idx >> 11, d = idx & 2047;
        wxt[idx] = (j < 33) ? f2bf(wx[d * 33 + j]) : (u16)0;
    }
}

// =======================================================================
// Deep-pipelined MFMA GEMM, C = A * Bt^T, with LDS reads hidden inside the
// MFMA pipe: phase q's MFMA cluster carries phase q+1's A-fragment ds_reads
// (areg ping-pong), pinned via sched_group_barrier {MFMA2, DS1, MFMA2}x4.
// B fragments read once per K-tile at q0 (exposed burst). Stage schedule and
// counted-vmcnt placement identical to the verified round-4 kernel.
// =======================================================================
template<int M_REP, int WARPS_M, int B_HALVES, bool OUT_BF16>
__global__ __launch_bounds__(512) void gemm_dp(
        const u16* __restrict__ A, const u16* __restrict__ Bt,
        void* __restrict__ Cout, int nbn_sh, int NT, int lda, int ldb, int ldc) {
    constexpr int WARPS_N = 8 / WARPS_M;
    constexpr int QPT = M_REP / 2;
    constexpr int WV_M = M_REP * 16;
    constexpr int BN = WARPS_N * 64;
    constexpr int B_T = BN * 64;              // u16 per B K-tile buffer

    __shared__ __align__(16) u16 As[2 * 16384];
    __shared__ __align__(16) u16 Bs[2 * B_T];

    const int tid = threadIdx.x;
    const int wave = tid >> 6;
    const int lane = tid & 63;
    const int wm = wave / WARPS_N, wn = wave % WARPS_N;
    const int fr = lane & 15, fq = lane >> 4;

    // T1 bijective XCD swizzle (gridDim.x % 8 == 0 at both call sites)
    const int nwg = gridDim.x;
    const int cpx = nwg >> 3;
    const int swz = (blockIdx.x & 7) * cpx + (blockIdx.x >> 3);
    const int bm = swz >> nbn_sh;
    const int bn = swz & ((1 << nbn_sh) - 1);

    // stage side: linear LDS dest, inverse-swizzled global source (rule #21)
    const int srow = tid >> 3;
    const int scol8 = ((tid & 7) ^ (srow & 7)) * 8;
    const u16* gA = A + (int64_t)(bm * 256 + srow) * lda + scol8;
    const u16* gB = Bt + (int64_t)(bn * BN + srow) * ldb + scol8;
    const int64_t lda64 = lda, ldb64 = ldb;

    // read side (swizzled): u16 index = row*64 + ((kk*4+fq)^(fr&7))*8
    const int ksw0 = ((fq) ^ (fr & 7)) * 8;
    const int ksw1 = ((4 + fq) ^ (fr & 7)) * 8;
    const int arow0 = (wm * WV_M + fr) * 64;
    const int brow0 = (wn * 64 + fr) * 64;

    auto STAGE_A_HALF = [&](int kt, int buf, int h) {   // 2 loads
#pragma unroll
        for (int j = 0; j < 2; ++j)
            gload_lds16(gA + (int64_t)(h * 128 + j * 64) * lda64 + kt * 64,
                        &As[buf * 16384 + h * 8192 + j * 4096 + tid * 8]);
    };
    auto STAGE_B_HALF = [&](int kt, int buf, int h) {   // 2 loads
#pragma unroll
        for (int j = 0; j < 2; ++j)
            gload_lds16(gB + (int64_t)(h * 128 + j * 64) * ldb64 + kt * 64,
                        &Bs[buf * B_T + h * 8192 + j * 4096 + tid * 8]);
    };

    f32x4 acc[M_REP][4] = {};

    // ---- prologue: A(0),B(0) -> buf0; B(1) -> buf1 ----
    STAGE_A_HALF(0, 0, 0); STAGE_A_HALF(0, 0, 1);
#pragma unroll
    for (int h = 0; h < B_HALVES; ++h) STAGE_B_HALF(0, 0, h);
#pragma unroll
    for (int h = 0; h < B_HALVES; ++h) STAGE_B_HALF(1, 1, h);
    if constexpr (B_HALVES == 2) { asm volatile("s_waitcnt vmcnt(4)" ::: "memory"); }
    else                         { asm volatile("s_waitcnt vmcnt(2)" ::: "memory"); }
    __builtin_amdgcn_s_barrier();

    const int NI = NT >> 1;
    for (int s = 0; s < NI; ++s) {
        const bool more = (s + 1 < NI);
#pragma unroll
        for (int t = 0; t < 2; ++t) {
            const u16* Ab = &As[t * 16384];
            const u16* Bb = &Bs[t * B_T];
            bf16x8 breg[4][2];
            bf16x8 areg[2][2][2];   // [pingpong][j][k-half], all-static indexing
#pragma unroll
            for (int q = 0; q < QPT; ++q) {
                const int p = q & 1;
                if (q == 0) {
                    // exposed reads: all B frags + A frags (rows 0,1)
#pragma unroll
                    for (int n = 0; n < 4; ++n) {
                        breg[n][0] = *(const bf16x8*)(Bb + brow0 + n * 1024 + ksw0);
                        breg[n][1] = *(const bf16x8*)(Bb + brow0 + n * 1024 + ksw1);
                    }
#pragma unroll
                    for (int j = 0; j < 2; ++j) {
                        areg[0][j][0] = *(const bf16x8*)(Ab + arow0 + j * 1024 + ksw0);
                        areg[0][j][1] = *(const bf16x8*)(Ab + arow0 + j * 1024 + ksw1);
                    }
                }
                __builtin_amdgcn_s_setprio(1);
                if (q + 1 < QPT) {
                    // next-phase A reads, to be interleaved into this MFMA cluster
#pragma unroll
                    for (int j = 0; j < 2; ++j) {
                        areg[p ^ 1][j][0] = *(const bf16x8*)(Ab + arow0 + (2 * (q + 1) + j) * 1024 + ksw0);
                        areg[p ^ 1][j][1] = *(const bf16x8*)(Ab + arow0 + (2 * (q + 1) + j) * 1024 + ksw1);
                    }
                }
#pragma unroll
                for (int j = 0; j < 2; ++j)
#pragma unroll
                    for (int n = 0; n < 4; ++n) {
                        acc[2 * q + j][n] = __builtin_amdgcn_mfma_f32_16x16x32_bf16(
                            areg[p][j][0], breg[n][0], acc[2 * q + j][n], 0, 0, 0);
                        acc[2 * q + j][n] = __builtin_amdgcn_mfma_f32_16x16x32_bf16(
                            areg[p][j][1], breg[n][1], acc[2 * q + j][n], 0, 0, 0);
                    }
                if (q + 1 < QPT) {
                    // T19 pin: 4x {MFMA 2, DS_READ 1, MFMA 2} = 16 MFMA + 4 DS
#pragma unroll
                    for (int g = 0; g < 4; ++g) {
                        __builtin_amdgcn_sched_group_barrier(0x008, 2, 0);
                        __builtin_amdgcn_sched_group_barrier(0x100, 1, 0);
                        __builtin_amdgcn_sched_group_barrier(0x008, 2, 0);
                    }
                }
                __builtin_amdgcn_s_setprio(0);
                // staging: exactly 2 global_load_lds per phase (round-4 schedule)
                if constexpr (QPT == 4) {
                    if (t == 0 && q == 0)         STAGE_A_HALF(2 * s + 1, 1, 0);
                    if (t == 0 && q == 1)         STAGE_A_HALF(2 * s + 1, 1, 1);
                    if (t == 0 && q == 2 && more) STAGE_B_HALF(2 * s + 2, 0, 0);
                    if (t == 0 && q == 3 && more) STAGE_B_HALF(2 * s + 2, 0, 1);
                    if (t == 1 && q == 0 && more) STAGE_A_HALF(2 * s + 2, 0, 0);
                    if (t == 1 && q == 1 && more) STAGE_A_HALF(2 * s + 2, 0, 1);
                    if (t == 1 && q == 2 && more) STAGE_B_HALF(2 * s + 3, 1, 0);
                    if (t == 1 && q == 3 && more) STAGE_B_HALF(2 * s + 3, 1, 1);
                } else {
                    if (t == 0 && q == 0)         STAGE_A_HALF(2 * s + 1, 1, 0);
                    if (t == 0 && q == 1) {       STAGE_A_HALF(2 * s + 1, 1, 1);
                        if (more)                 STAGE_B_HALF(2 * s + 2, 0, 0); }
                    if (t == 1 && q == 0 && more) STAGE_A_HALF(2 * s + 2, 0, 0);
                    if (t == 1 && q == 1 && more) { STAGE_A_HALF(2 * s + 2, 0, 1);
                                                    STAGE_B_HALF(2 * s + 3, 1, 0); }
                }
                if (q == QPT - 1) {   // counted waits only at K-tile ends
                    if (more) {
                        if constexpr (B_HALVES == 2) { asm volatile("s_waitcnt vmcnt(4)" ::: "memory"); }
                        else                         { asm volatile("s_waitcnt vmcnt(2)" ::: "memory"); }
                    } else {
                        asm volatile("s_waitcnt vmcnt(0)" ::: "memory");
                    }
                }
                __builtin_amdgcn_s_barrier();
            }
        }
    }

    // ---- epilogue ----
#pragma unroll
    for (int m = 0; m < M_REP; ++m) {
#pragma unroll
        for (int n = 0; n < 4; ++n) {
            const int col = bn * BN + wn * 64 + n * 16 + fr;
#pragma unroll
            for (int r = 0; r < 4; ++r) {
                const int row = bm * 256 + wm * WV_M + m * 16 + fq * 4 + r;
                if constexpr (OUT_BF16)
                    ((u16*)Cout)[(int64_t)row * ldc + col] = f2bf(acc[m][n][r]);
                else
                    ((float*)Cout)[(int64_t)row * ldc + col] = acc[m][n][r];
            }
        }
    }
}

// ---------------- depthwise conv(4) + bias + SiLU ----------------
__global__ __launch_bounds__(256) void conv_silu_k(
        const u16* __restrict__ xz, const float* __restrict__ cw,
        const float* __restrict__ cb, u16* __restrict__ xc) {
    const int blk = blockIdx.x;
    const int b = blk >> 9;
    const int l0 = (blk & 511) << 2;
    const int d0 = threadIdx.x * 8;
    float w[8][4], bias[8];
#pragma unroll
    for (int j = 0; j < 8; j++) {
        float4 wv = *(const float4*)&cw[(d0 + j) * 4];
        w[j][0] = wv.x; w[j][1] = wv.y; w[j][2] = wv.z; w[j][3] = wv.w;
        bias[j] = cb[d0 + j];
    }
    float xp[7][8];
#pragma unroll
    for (int r = 0; r < 7; r++) {
        int l = l0 - 3 + r;
        if (l < 0) {
#pragma unroll
            for (int j = 0; j < 8; j++) xp[r][j] = 0.f;
        } else {
            ushort8v v = *(const ushort8v*)&xz[((int64_t)(b * 2048 + l)) * 4096 + d0];
#pragma unroll
            for (int j = 0; j < 8; j++) xp[r][j] = bf2f(v[j]);
        }
    }
#pragma unroll
    for (int li = 0; li < 4; li++) {
        ushort8v o;
#pragma unroll
        for (int j = 0; j < 8; j++) {
            float s = bias[j];
#pragma unroll
            for (int k = 0; k < 4; k++) s += w[j][k] * xp[li + k][j];
            o[j] = f2bf(silu_f(s));
        }
        *(ushort8v*)&xc[((int64_t)(b * 2048 + l0 + li)) * 2048 + d0] = o;
    }
}

// ---------------- ssm projection (K split by 4), spart: [4][8192][48] ----------------
__global__ __launch_bounds__(256) void ssm_proj_k(
        const u16* __restrict__ xc, const u16* __restrict__ wxt,
        float* __restrict__ spart) {
    const int gw = (blockIdx.x << 2) + (threadIdx.x >> 6);
    const int lane = threadIdx.x & 63;
    const int rb = gw >> 2, kc = gw & 3;
    const int fr = lane & 15, fq = lane >> 4;
    const u16* ap = xc + (int64_t)(rb * 16 + fr) * 2048 + kc * 512 + fq * 8;
    const u16* bp = wxt + (int64_t)fr * 2048 + kc * 512 + fq * 8;
    f32x4 acc0 = {}, acc1 = {}, acc2 = {};
#pragma unroll 4
    for (int k = 0; k < 512; k += 32) {
        bf16x8 av = *(const bf16x8*)(ap + k);
        bf16x8 b0 = *(const bf16x8*)(bp + k);
        bf16x8 b1 = *(const bf16x8*)(bp + 16 * 2048 + k);
        bf16x8 b2 = *(const bf16x8*)(bp + 32 * 2048 + k);
        acc0 = __builtin_amdgcn_mfma_f32_16x16x32_bf16(av, b0, acc0, 0, 0, 0);
        acc1 = __builtin_amdgcn_mfma_f32_16x16x32_bf16(av, b1, acc1, 0, 0, 0);
        acc2 = __builtin_amdgcn_mfma_f32_16x16x32_bf16(av, b2, acc2, 0, 0, 0);
    }
    float* sp = spart + ((int64_t)kc * 8192 + rb * 16) * 48;
#pragma unroll
    for (int r = 0; r < 4; r++) {
        int ro = (fq * 4 + r) * 48;
        sp[ro + fr] = acc0[r];
        sp[ro + 16 + fr] = acc1[r];
        sp[ro + 32 + fr] = acc2[r];
    }
}

__global__ __launch_bounds__(256) void ssm_fin_k(
        const float* __restrict__ spart, float* __restrict__ dB,
        float* __restrict__ Cm) {
    const int row = blockIdx.x * 256 + threadIdx.x;
    const float* sp = spart + (int64_t)row * 48;
    float s[33];
#pragma unroll
    for (int j = 0; j < 33; j++)
        s[j] = sp[j] + sp[8192 * 48 + j] + sp[2 * 8192 * 48 + j] + sp[3 * 8192 * 48 + j];
    float d0v = s[0];
    float delta = (d0v > 20.f) ? d0v : log1pf(__expf(d0v));
#pragma unroll
    for (int n = 0; n < 16; n++) {
        dB[(int64_t)row * 16 + n] = delta * s[1 + n] * (1.0f / 2048.0f);
        Cm[(int64_t)row * 16 + n] = s[17 + n];
    }
}

__global__ __launch_bounds__(256) void h_part_k(
        const u16* __restrict__ xc, const float* __restrict__ dB,
        float* __restrict__ hp) {
    const int blk = blockIdx.x;
    const int dt = blk & 7, b = (blk >> 3) & 3, lc = blk >> 5;
    const int d = dt * 256 + threadIdx.x;
    const u16* xp = xc + ((int64_t)(b * 2048 + lc * 256)) * 2048 + d;
    const float* dbp = dB + (int64_t)(b * 2048 + lc * 256) * 16;
    float acc[16] = {};
    for (int l = 0; l < 256; l++) {
        float xv = bf2f(xp[(int64_t)l * 2048]);
#pragma unroll
        for (int n = 0; n < 16; n++) acc[n] += xv * dbp[l * 16 + n];
    }
    float* o = hp + ((int64_t)((lc * 4 + b) * 2048 + d)) * 16;
#pragma unroll
    for (int n = 0; n < 16; n++) o[n] = acc[n];
}

__global__ void h_red_k(const float* __restrict__ hp, float* __restrict__ h) {
    const int i = blockIdx.x * 256 + threadIdx.x;  // < 131072
    float s = 0.f;
#pragma unroll
    for (int c = 0; c < 8; c++) s += hp[(int64_t)c * 131072 + i];
    h[i] = s;
}

__global__ __launch_bounds__(256) void y_gate_k(
        u16* __restrict__ xz, const u16* __restrict__ xc,
        const float* __restrict__ h, const float* __restrict__ Cm,
        const float* __restrict__ Dp) {
    const int blk = blockIdx.x;
    const int lc = blk & 63, dt = (blk >> 6) & 1, b = blk >> 7;
    const int d0 = dt * 1024 + threadIdx.x * 4;
    const float* hpp = h + ((int64_t)(b * 2048 + d0)) * 16;
    float hreg[4][16];
#pragma unroll
    for (int i = 0; i < 4; i++)
#pragma unroll
        for (int n = 0; n < 16; n++) hreg[i][n] = hpp[i * 16 + n];
    float Dv[4];
#pragma unroll
    for (int i = 0; i < 4; i++) Dv[i] = Dp[d0 + i];
    __shared__ float Cs[32][16];
    if (threadIdx.x < 128)
        ((float4*)&Cs[0][0])[threadIdx.x] =
            ((const float4*)(Cm + (int64_t)(b * 2048 + lc * 32) * 16))[threadIdx.x];
    __syncthreads();
    for (int li = 0; li < 32; li++) {
        const int64_t rowz = (int64_t)(b * 2048 + lc * 32 + li);
        ushort4v xcv = *(const ushort4v*)&xc[rowz * 2048 + d0];
        ushort4v zv = *(const ushort4v*)&xz[rowz * 4096 + 2048 + d0];
        ushort4v o;
#pragma unroll
        for (int i = 0; i < 4; i++) {
            float s = Dv[i] * bf2f(xcv[i]);
#pragma unroll
            for (int n = 0; n < 16; n++) s += hreg[i][n] * Cs[li][n];
            o[i] = f2bf(s * silu_f(bf2f(zv[i])));
        }
        *(ushort4v*)&xz[rowz * 4096 + d0] = o;
    }
}

extern "C" void kernel_launch(void* const* d_in, const int* in_sizes, int n_in,
                              void* d_out, int out_size, void* d_ws, size_t ws_size,
                              hipStream_t stream) {
    (void)in_sizes; (void)n_in; (void)out_size; (void)ws_size;
    const float* x      = (const float*)d_in[0];
    const float* W_in   = (const float*)d_in[1];
    const float* conv_w = (const float*)d_in[2];
    const float* conv_b = (const float*)d_in[3];
    const float* W_xp   = (const float*)d_in[4];
    const float* Dp     = (const float*)d_in[6];   // d_in[5] = A_log, unused by reference
    const float* W_out  = (const float*)d_in[7];
    float* out = (float*)d_out;
    char* ws = (char*)d_ws;

    u16*   x_bf   = (u16*)(ws);                   // 16,777,216 B (dead after GEMM1)
    float* spart  = (float*)(ws);                 // alias: 6,291,456
    float* dB     = (float*)(ws + 6291456);       // 524,288
    float* Cm     = (float*)(ws + 6815744);       // 524,288
    float* hp     = (float*)(ws + 7340032);       // 4,194,304
    float* h      = (float*)(ws + 11534336);      // 524,288
    u16*   Wt_in  = (u16*)(ws + 16777216);        // 8,388,608
    u16*   Wt_out = (u16*)(ws + 25165824);        // 4,194,304
    u16*   Wxt    = (u16*)(ws + 29360128);        // 196,608
    u16*   xz     = (u16*)(ws + 29556736);        // 67,108,864
    u16*   xcv    = (u16*)(ws + 96665600);        // 33,554,432  (total ~130 MB)

    prep_k<<<14720, 256, 0, stream>>>(x, x_bf, W_in, Wt_in, W_out, Wt_out, W_xp, Wxt);
    // xz = x @ W_in : M=8192 N=4096 K=1024; grid (8192/256)*(4096/256)=512
    gemm_dp<8, 2, 2, true><<<512, 512, 0, stream>>>(x_bf, Wt_in, xz, 4, 16, 1024, 1024, 4096);
    conv_silu_k<<<2048, 256, 0, stream>>>(xz, conv_w, conv_b, xcv);
    ssm_proj_k<<<512, 256, 0, stream>>>(xcv, Wxt, spart);
    ssm_fin_k<<<32, 256, 0, stream>>>(spart, dB, Cm);
    h_part_k<<<256, 256, 0, stream>>>(xcv, dB, hp);
    h_red_k<<<512, 256, 0, stream>>>(hp, h);
    y_gate_k<<<512, 256, 0, stream>>>(xz, xcv, h, Cm, Dp);
    // out = y @ W_out : M=8192 N=1024 K=2048; grid (8192/256)*(1024/128)=256
    gemm_dp<4, 4, 1, false><<<256, 512, 0, stream>>>(xz, Wt_out, out, 3, 32, 4096, 2048, 1024);
}